// Round 6
// baseline (896.511 us; speedup 1.0000x reference)
//
#include <hip/hip_runtime.h>
#include <math.h>

#define NN    50000
#define DD    64
#define HH    4
#define E_RES 400000
#define E_SEQ 100000
#define E_KNN 400000
#define SCH   4096
#define SNB   ((NN + SCH - 1)/SCH)   // 13 chunks per relation
#define RPS   (NN + 4)               // rowptr stride (16B-aligned per relation)
#define WRSTRIDE 8968                // floats per relation in wbuf

typedef __attribute__((ext_vector_type(8))) short short8;
typedef __attribute__((ext_vector_type(4))) float floatx4;

__device__ inline unsigned short f2bf(float f){
  union{float f; unsigned u;} v; v.f=f;
  unsigned r = v.u + 0x7FFF + ((v.u>>16)&1);
  return (unsigned short)(r>>16);
}
__device__ inline float bf2f(unsigned short u){
  union{unsigned u; float f;} v; v.u=(unsigned)u<<16; return v.f;
}

// ---------------- CSR build ----------------
__global__ void k_hist(const int* __restrict__ dst, int E, int* __restrict__ cnt){
  int i = blockIdx.x*256 + threadIdx.x;
  if(i<E) atomicAdd(&cnt[dst[i]], 1);
}

__global__ void __launch_bounds__(256)
k_blocksum(const int* __restrict__ hist, int* __restrict__ bsums){
  int r = blockIdx.x / SNB, b = blockIdx.x % SNB;
  const int* cnt = hist + r*NN;
  int t = threadIdx.x;
  int end = min((b+1)*SCH, NN);
  int s = 0;
  for(int j = b*SCH + t; j < end; j += 256) s += cnt[j];
  __shared__ int sh[4];
  for(int off=32; off; off>>=1) s += __shfl_down(s, off, 64);
  int lane = t & 63, w = t >> 6;
  if(lane==0) sh[w]=s;
  __syncthreads();
  if(t==0) bsums[blockIdx.x] = sh[0]+sh[1]+sh[2]+sh[3];
}

__global__ void __launch_bounds__(256)
k_scanwrite(const int* __restrict__ hist, const int* __restrict__ bsums,
            int* __restrict__ rowptr, int* __restrict__ cursor){
  int r = blockIdx.x / SNB, b = blockIdx.x % SNB;
  const int* cnt = hist + r*NN;
  int* rp  = rowptr + r*RPS;
  int* cur = cursor + r*NN;
  __shared__ int sh_off;
  __shared__ int wtot[4];
  int t = threadIdx.x;
  if(t==0){
    int o=0, tot=0;
    for(int i=0;i<SNB;i++){ int v=bsums[r*SNB+i]; if(i<b) o+=v; tot+=v; }
    sh_off=o;
    if(b==0) rp[NN]=tot;
  }
  int base = b*SCH + t*16;
  int v[16];
  bool full = (base+16 <= NN);
  if(full){
    int4 a0=((const int4*)cnt)[base/4+0];
    int4 a1=((const int4*)cnt)[base/4+1];
    int4 a2=((const int4*)cnt)[base/4+2];
    int4 a3=((const int4*)cnt)[base/4+3];
    v[0]=a0.x;v[1]=a0.y;v[2]=a0.z;v[3]=a0.w;
    v[4]=a1.x;v[5]=a1.y;v[6]=a1.z;v[7]=a1.w;
    v[8]=a2.x;v[9]=a2.y;v[10]=a2.z;v[11]=a2.w;
    v[12]=a3.x;v[13]=a3.y;v[14]=a3.z;v[15]=a3.w;
  } else {
    for(int j=0;j<16;j++){ int idx=base+j; v[j]=(idx<NN)?cnt[idx]:0; }
  }
  int loc=0;
  #pragma unroll
  for(int j=0;j<16;j++) loc += v[j];
  int lane = t & 63, w = t >> 6;
  int inc = loc;
  for(int off=1; off<64; off<<=1){ int n=__shfl_up(inc, off, 64); if(lane>=off) inc+=n; }
  if(lane==63) wtot[w]=inc;
  __syncthreads();
  int woff=0;
  for(int i=0;i<w;i++) woff += wtot[i];
  int run = sh_off + woff + inc - loc;
  if(full){
    int o[16];
    #pragma unroll
    for(int j=0;j<16;j++){ o[j]=run; run+=v[j]; }
    ((int4*)rp )[base/4+0]=make_int4(o[0],o[1],o[2],o[3]);
    ((int4*)rp )[base/4+1]=make_int4(o[4],o[5],o[6],o[7]);
    ((int4*)rp )[base/4+2]=make_int4(o[8],o[9],o[10],o[11]);
    ((int4*)rp )[base/4+3]=make_int4(o[12],o[13],o[14],o[15]);
    ((int4*)cur)[base/4+0]=make_int4(o[0],o[1],o[2],o[3]);
    ((int4*)cur)[base/4+1]=make_int4(o[4],o[5],o[6],o[7]);
    ((int4*)cur)[base/4+2]=make_int4(o[8],o[9],o[10],o[11]);
    ((int4*)cur)[base/4+3]=make_int4(o[12],o[13],o[14],o[15]);
  } else {
    for(int j=0;j<16;j++){
      int idx=base+j;
      if(idx<NN){ rp[idx]=run; cur[idx]=run; run+=v[j]; }
    }
  }
}

__global__ void k_scatter(const int* __restrict__ src, const int* __restrict__ dst,
                          int E, int* __restrict__ cursor, int* __restrict__ csr){
  int i = blockIdx.x*256 + threadIdx.x;
  if(i<E){ int pos = atomicAdd(&cursor[dst[i]],1); csr[pos]=src[i]; }
}

// ---------------- BN stats ----------------
__global__ void k_bnstats(const float* __restrict__ x, float* __restrict__ stats){
  __shared__ float sh[512];
  int t = threadIdx.x, col = t & 63, rg = t >> 6;
  float s=0.f, q=0.f;
  for(int row = blockIdx.x*4 + rg; row < NN; row += gridDim.x*4){
    float v = x[(size_t)row*64 + col]; s += v; q += v*v;
  }
  sh[t]=s; sh[256+t]=q; __syncthreads();
  if(rg==0){
    s = sh[col]+sh[64+col]+sh[128+col]+sh[192+col];
    q = sh[256+col]+sh[320+col]+sh[384+col]+sh[448+col];
    atomicAdd(&stats[col], s); atomicAdd(&stats[64+col], q);
  }
}

// ---------------- fold BN into weights (parallel) ---------------------------
__global__ void __launch_bounds__(256)
k_prep2(const float* __restrict__ stats, const float* __restrict__ g,
        const float* __restrict__ be, const float* __restrict__ W,
        const float* __restrict__ al, const float* __restrict__ ar,
        const float* __restrict__ b, const float* __restrict__ rW,
        float* __restrict__ wbuf){
  __shared__ float scale[64], shift[64];
  __shared__ float red[256];
  int t = threadIdx.x;
  if(t<64){
    float mu  = stats[t]*(1.0f/NN);
    float var = stats[64+t]*(1.0f/NN) - mu*mu;
    float sc  = g[t]*rsqrtf(var + 1e-5f);
    scale[t]=sc; shift[t]=be[t]-mu*sc;
  }
  __syncthreads();
  int bid = blockIdx.x;
  if(bid < 12){
    int r = bid >> 2, c0 = (bid & 3)*64;
    float* fr = wbuf + 4160 + r*WRSTRIDE;
    unsigned short* Wt = (unsigned short*)fr;
    float* bo = fr + 8192;
    int cl = c0 + (t & 63), kg = t >> 6;
    int h = cl >> 6, d = cl & 63, cp = d*4 + h;
    float bias = 0.f;
    #pragma unroll
    for(int j=0;j<16;j++){
      int k = kg*16 + j;
      float w = W[((size_t)(r*64+k))*256 + cl];
      bias += shift[k]*w;
      Wt[cp*64 + k] = f2bf(scale[k]*w);
    }
    red[t]=bias; __syncthreads();
    if(kg==0) bo[cp] = red[t] + red[t+64] + red[t+128] + red[t+192];
  } else if(bid < 18){
    int wv = (bid-12)*4 + (t>>6);        // 0..23
    int r = wv >> 3, cc = wv & 7, h = cc & 3, k = t & 63;
    const float* av = ((cc>=4)?ar:al) + (r*HH+h)*64;
    const float* Wk = W + ((size_t)(r*64+k))*256 + h*64;
    float w=0.f;
    for(int d2=0; d2<64; d2++) w += Wk[d2]*av[d2];
    float* fr = wbuf + 4160 + r*WRSTRIDE;
    (fr + 8448)[cc*64 + k] = scale[k]*w;   // Wel
    float bp = shift[k]*w;
    for(int off=32; off; off>>=1) bp += __shfl_down(bp, off, 64);
    if(k==0) (fr + 8960)[cc] = bp;         // biasE
  } else {
    int db = (bid-18)*16;
    int d = db + (t & 15), kg = t >> 4;
    float bias = 0.f;
    #pragma unroll
    for(int j=0;j<4;j++){
      int k = kg*4 + j;
      float w = 0.f;
      for(int r=0;r<3;r++)
        for(int h=0;h<HH;h++)
          w += rW[((size_t)(r*64+k))*256 + h*64 + d];
      w *= 0.25f;
      bias += shift[k]*w;
      wbuf[k*64+d] = scale[k]*w;
    }
    red[t]=bias; __syncthreads();
    if(t<16){
      float s=0.f;
      for(int i=t;i<256;i+=16) s += red[i];
      int dd = db + t;
      float bb=0.f;
      for(int r=0;r<3;r++) for(int h=0;h<HH;h++) bb += b[r*256 + h*64 + dd];
      wbuf[4096+dd] = s + 0.25f*bb;
    }
  }
}

// ---------------- cast activations f32 -> bf16 ------------------------------
__global__ void __launch_bounds__(256)
k_cast(const float* __restrict__ X, unsigned short* __restrict__ out){
  int i = blockIdx.x*256 + threadIdx.x;   // one float4 per thread
  float4 v = ((const float4*)X)[i];
  ushort4 o;
  o.x=f2bf(v.x); o.y=f2bf(v.y); o.z=f2bf(v.z); o.w=f2bf(v.w);
  ((ushort4*)out)[i]=o;
}

// ---------------- MFMA matmul: Ybf[N,256] = Abf[N,64] @ W + bias ------------
__global__ void __launch_bounds__(256)
k_mfmaC(const unsigned short* __restrict__ Abf, const float* __restrict__ fr,
        unsigned short* __restrict__ Ybf){
  const unsigned short* Wt = (const unsigned short*)fr;
  const float* biasC = fr + 8192;
  int t = threadIdx.x;
  int wv = t>>6, lane = t&63;
  int m = lane&15, kq = lane>>4;       // kq=0..3
  int row = blockIdx.x*64 + wv*16 + m;
  int rc = row < NN ? row : NN-1;
  short8 a0 = *(const short8*)(Abf + (size_t)rc*64 + kq*8);
  short8 a1 = *(const short8*)(Abf + (size_t)rc*64 + 32 + kq*8);
  int orow = blockIdx.x*64 + wv*16 + kq*4;
  for(int ct=0; ct<16; ct++){
    int col = ct*16 + m;
    const unsigned short* wp = Wt + (size_t)col*64 + kq*8;
    short8 b0 = *(const short8*)(wp);
    short8 b1 = *(const short8*)(wp + 32);
    floatx4 acc = {0.f,0.f,0.f,0.f};
    acc = __builtin_amdgcn_mfma_f32_16x16x32_bf16(a0, b0, acc, 0,0,0);
    acc = __builtin_amdgcn_mfma_f32_16x16x32_bf16(a1, b1, acc, 0,0,0);
    float bs = biasC[col];
    #pragma unroll
    for(int ri=0; ri<4; ri++){
      int ro = orow + ri;
      if(ro < NN) Ybf[(size_t)ro*256 + col] = f2bf(acc[ri] + bs);
    }
  }
}

// ---------------- el/er: EL[N,8] = A[N,64] @ Wel (f32, exact) ---------------
__global__ void __launch_bounds__(256)
k_el(const float* __restrict__ A, const float* __restrict__ fr,
     float* __restrict__ EL){
  const float* Wel = fr + 8448;
  const float* biasE = fr + 8960;
  __shared__ float sw[512];
  __shared__ float sb[8];
  int t = threadIdx.x;
  sw[t]=Wel[t]; sw[256+t]=Wel[256+t];
  if(t<8) sb[t]=biasE[t];
  __syncthreads();
  int n = blockIdx.x*256 + t;
  if(n>=NN) return;
  float acc[8];
  #pragma unroll
  for(int c=0;c<8;c++) acc[c]=sb[c];
  const float4* Ar = (const float4*)(A + (size_t)n*64);
  #pragma unroll
  for(int kq=0;kq<16;kq++){
    float4 a = Ar[kq];
    #pragma unroll
    for(int c=0;c<8;c++){
      const float* w = sw + c*64 + kq*4;
      acc[c] += a.x*w[0] + a.y*w[1] + a.z*w[2] + a.w*w[3];
    }
  }
  ((float4*)EL)[n*2]   = make_float4(acc[0],acc[1],acc[2],acc[3]);
  ((float4*)EL)[n*2+1] = make_float4(acc[4],acc[5],acc[6],acc[7]);
}

// ---------------- matmul: [NN,64] @ [64,64] + bias (opt relu) ----------------
__global__ void __launch_bounds__(256)
k_matmul64(const float* __restrict__ A, const float* __restrict__ W,
           const float* __restrict__ bias, float* __restrict__ Y, int relu){
  __shared__ float xs[4096];
  int t = threadIdx.x;
  int row0 = blockIdx.x*64;
  for(int f=t; f<1024; f+=256){
    int r=f>>4; int row=row0+r;
    float4 v = (row<NN) ? ((const float4*)A)[(size_t)row*16 + (f&15)]
                        : make_float4(0.f,0.f,0.f,0.f);
    ((float4*)xs)[f]=v;
  }
  __syncthreads();
  int c = t & 63, rg = t >> 6;
  float wreg[64];
  #pragma unroll
  for(int k=0;k<64;k++) wreg[k]=W[k*64+c];
  float bs = bias[c];
  for(int r=rg*16; r<rg*16+16; r++){
    int row=row0+r; if(row>=NN) continue;
    float acc=bs;
    #pragma unroll
    for(int k=0;k<64;k++) acc += xs[r*64+k]*wreg[k];
    if(relu) acc=fmaxf(acc,0.f);
    Y[(size_t)row*64+c]=acc;
  }
}

// ---- fused softmax + weighted gather: one WAVE per dst node ----------------
// Pass1: lanes parallel over edges -> online (m,s) -> butterfly combine.
// Pass2: lanes compute alpha into LDS (padded mult-of-4, alpha=0), then
//        broadcast-read LDS and issue 4 independent Y gathers per step.
__global__ void __launch_bounds__(256)
k_aggf(const unsigned short* __restrict__ Ybf, const float* __restrict__ EL,
       const int* __restrict__ rowptr, const int* __restrict__ csr,
       float* __restrict__ hacc){
  __shared__ int   s_src[4][64];
  __shared__ float4 s_alpha[4][64];
  int wid  = (blockIdx.x*256 + threadIdx.x) >> 6;
  int lane = threadIdx.x & 63;
  int wv   = threadIdx.x >> 6;
  if(wid>=NN) return;
  int beg = rowptr[wid], end = rowptr[wid+1];
  int deg = end - beg;
  if(deg<=0) return;
  float4 er = ((const float4*)EL)[wid*2+1];
  // ---- pass 1: parallel online softmax stats ----
  float4 m = make_float4(-1e30f,-1e30f,-1e30f,-1e30f);
  float4 s = make_float4(0.f,0.f,0.f,0.f);
  for(int i=beg+lane; i<end; i+=64){
    int src = csr[i];
    float4 el = ((const float4*)EL)[src*2];
    float e0=el.x+er.x, e1=el.y+er.y, e2=el.z+er.z, e3=el.w+er.w;
    e0 = e0>0.f? e0 : 0.2f*e0;
    e1 = e1>0.f? e1 : 0.2f*e1;
    e2 = e2>0.f? e2 : 0.2f*e2;
    e3 = e3>0.f? e3 : 0.2f*e3;
    float n0=fmaxf(m.x,e0); s.x=s.x*__expf(m.x-n0)+__expf(e0-n0); m.x=n0;
    float n1=fmaxf(m.y,e1); s.y=s.y*__expf(m.y-n1)+__expf(e1-n1); m.y=n1;
    float n2=fmaxf(m.z,e2); s.z=s.z*__expf(m.z-n2)+__expf(e2-n2); m.z=n2;
    float n3=fmaxf(m.w,e3); s.w=s.w*__expf(m.w-n3)+__expf(e3-n3); m.w=n3;
  }
  #pragma unroll
  for(int mask=1; mask<64; mask<<=1){
    float mx=__shfl_xor(m.x,mask), my=__shfl_xor(m.y,mask),
          mz=__shfl_xor(m.z,mask), mw=__shfl_xor(m.w,mask);
    float sx=__shfl_xor(s.x,mask), sy=__shfl_xor(s.y,mask),
          sz=__shfl_xor(s.z,mask), sw=__shfl_xor(s.w,mask);
    float M0=fmaxf(m.x,mx), M1=fmaxf(m.y,my), M2=fmaxf(m.z,mz), M3=fmaxf(m.w,mw);
    s.x = s.x*__expf(m.x-M0) + sx*__expf(mx-M0);
    s.y = s.y*__expf(m.y-M1) + sy*__expf(my-M1);
    s.z = s.z*__expf(m.z-M2) + sz*__expf(mz-M2);
    s.w = s.w*__expf(m.w-M3) + sw*__expf(mw-M3);
    m.x=M0; m.y=M1; m.z=M2; m.w=M3;
  }
  float4 rs = make_float4(1.f/s.x, 1.f/s.y, 1.f/s.z, 1.f/s.w);
  // ---- pass 2: chunked alpha->LDS, then unrolled gather ----
  float aa0=0.f, aa1=0.f, aa2=0.f, aa3=0.f;
  for(int c=beg; c<end; c+=64){
    int L = min(64, end-c);
    int Lpad = (L+3)&~3;
    if(lane < Lpad){
      bool valid = lane < L;
      int src = valid ? csr[c+lane] : csr[beg];
      float4 al4 = make_float4(0.f,0.f,0.f,0.f);
      if(valid){
        float4 el = ((const float4*)EL)[src*2];
        float e0=el.x+er.x, e1=el.y+er.y, e2=el.z+er.z, e3=el.w+er.w;
        e0 = e0>0.f? e0 : 0.2f*e0;
        e1 = e1>0.f? e1 : 0.2f*e1;
        e2 = e2>0.f? e2 : 0.2f*e2;
        e3 = e3>0.f? e3 : 0.2f*e3;
        al4 = make_float4(__expf(e0-m.x)*rs.x, __expf(e1-m.y)*rs.y,
                          __expf(e2-m.z)*rs.z, __expf(e3-m.w)*rs.w);
      }
      s_src[wv][lane]=src; s_alpha[wv][lane]=al4;
    }
    __builtin_amdgcn_wave_barrier();
    for(int j=0; j<Lpad; j+=4){
      int  i0=s_src[wv][j],   i1=s_src[wv][j+1], i2=s_src[wv][j+2], i3=s_src[wv][j+3];
      float4 A0=s_alpha[wv][j],   A1=s_alpha[wv][j+1],
             A2=s_alpha[wv][j+2], A3=s_alpha[wv][j+3];
      ushort4 y0 = *(const ushort4*)(Ybf + ((size_t)i0<<8) + lane*4);
      ushort4 y1 = *(const ushort4*)(Ybf + ((size_t)i1<<8) + lane*4);
      ushort4 y2 = *(const ushort4*)(Ybf + ((size_t)i2<<8) + lane*4);
      ushort4 y3 = *(const ushort4*)(Ybf + ((size_t)i3<<8) + lane*4);
      aa0 += A0.x*bf2f(y0.x)+A0.y*bf2f(y0.y)+A0.z*bf2f(y0.z)+A0.w*bf2f(y0.w);
      aa1 += A1.x*bf2f(y1.x)+A1.y*bf2f(y1.y)+A1.z*bf2f(y1.z)+A1.w*bf2f(y1.w);
      aa2 += A2.x*bf2f(y2.x)+A2.y*bf2f(y2.y)+A2.z*bf2f(y2.z)+A2.w*bf2f(y2.w);
      aa3 += A3.x*bf2f(y3.x)+A3.y*bf2f(y3.y)+A3.z*bf2f(y3.z)+A3.w*bf2f(y3.w);
    }
    __builtin_amdgcn_wave_barrier();
  }
  hacc[(size_t)wid*64 + lane] += 0.25f*(aa0+aa1+aa2+aa3);
}

extern "C" void kernel_launch(void* const* d_in, const int* in_sizes, int n_in,
                              void* d_out, int out_size, void* d_ws, size_t ws_size,
                              hipStream_t stream){
  const float* x      =(const float*)d_in[0];
  const int* src_res  =(const int*)d_in[1];
  const int* dst_res  =(const int*)d_in[2];
  const int* src_seq  =(const int*)d_in[3];
  const int* dst_seq  =(const int*)d_in[4];
  const int* src_knn  =(const int*)d_in[5];
  const int* dst_knn  =(const int*)d_in[6];
  const float* W0 =(const float*)d_in[7];
  const float* al0=(const float*)d_in[8];
  const float* ar0=(const float*)d_in[9];
  const float* b0 =(const float*)d_in[10];
  const float* rW0=(const float*)d_in[11];
  const float* W1 =(const float*)d_in[12];
  const float* al1=(const float*)d_in[13];
  const float* ar1=(const float*)d_in[14];
  const float* b1 =(const float*)d_in[15];
  const float* rW1=(const float*)d_in[16];
  const float* fcW0=(const float*)d_in[17];
  const float* fcb0=(const float*)d_in[18];
  const float* fcW1=(const float*)d_in[19];
  const float* fcb1=(const float*)d_in[20];
  const float* g0 =(const float*)d_in[21];
  const float* be0=(const float*)d_in[22];
  const float* g1 =(const float*)d_in[23];
  const float* be1=(const float*)d_in[24];

  char* ws=(char*)d_ws;
  int*   hist   =(int*)  (ws+0);               // 3*NN ints
  float* stats0 =(float*)(ws+600000);
  float* stats1 =(float*)(ws+600512);
  int*   rowptr =(int*)  (ws+601024);          // 3*RPS ints
  int*   cursor =(int*)  (ws+1201088);
  int*   csr    =(int*)  (ws+1801088);         // 900000 ints
  float* wbuf   =(float*)(ws+5401088);         // 31064 f
  int*   bsums  =(int*)  (ws+5525344);         // 39 ints
  unsigned short* Abf =(unsigned short*)(ws+5526528);  // NN*64 bf16 = 6.4MB
  unsigned short* Ybf =(unsigned short*)(ws+11926528UL); // NN*256 bf16 = 25.6MB
  float* hacc   =(float*)(ws+37526528UL);      // NN*64 f
  float* xbuf   =(float*)(ws+50326528UL);      // NN*64 f
  float* EL     =(float*)(ws+63126528UL);      // NN*8 f

  hipMemsetAsync(ws, 0, 601024, stream);  // hist + both stats buffers

  k_hist<<<(E_RES+255)/256,256,0,stream>>>(dst_res,E_RES,hist);
  k_hist<<<(E_SEQ+255)/256,256,0,stream>>>(dst_seq,E_SEQ,hist+NN);
  k_hist<<<(E_KNN+255)/256,256,0,stream>>>(dst_knn,E_KNN,hist+2*NN);
  k_blocksum<<<3*SNB,256,0,stream>>>(hist,bsums);
  k_scanwrite<<<3*SNB,256,0,stream>>>(hist,bsums,rowptr,cursor);
  k_scatter<<<(E_RES+255)/256,256,0,stream>>>(src_res,dst_res,E_RES,cursor,csr);
  k_scatter<<<(E_SEQ+255)/256,256,0,stream>>>(src_seq,dst_seq,E_SEQ,cursor+NN,csr+E_RES);
  k_scatter<<<(E_KNN+255)/256,256,0,stream>>>(src_knn,dst_knn,E_KNN,cursor+2*NN,csr+E_RES+E_SEQ);

  const int MBLK=(NN+63)/64;   // 782
  const int NBLK=(NN+255)/256; // 196
  const int CBLK=(NN*64)/(256*4); // 3125 (exact)
  const int ABLK=(NN*64)/256;  // 12500 (exact)
  // ---- layer 1 ----
  k_bnstats<<<256,256,0,stream>>>(x,stats0);
  k_prep2<<<22,256,0,stream>>>(stats0,g0,be0,W0,al0,ar0,b0,rW0,wbuf);
  k_cast<<<CBLK,256,0,stream>>>(x,Abf);
  k_matmul64<<<MBLK,256,0,stream>>>(x,wbuf,wbuf+4096,hacc,0);   // residual+bias, head-meaned
  for(int r=0;r<3;r++){
    float* fr=wbuf+4160+r*WRSTRIDE;
    int csroff=(r==0)?0:(r==1)?E_RES:(E_RES+E_SEQ);
    k_mfmaC<<<MBLK,256,0,stream>>>(Abf,fr,Ybf);
    k_el<<<NBLK,256,0,stream>>>(x,fr,EL);
    k_aggf<<<ABLK,256,0,stream>>>(Ybf,EL,rowptr+r*RPS,csr+csroff,hacc);
  }
  k_matmul64<<<MBLK,256,0,stream>>>(hacc,fcW0,fcb0,xbuf,1);
  // ---- layer 2 ----
  k_bnstats<<<256,256,0,stream>>>(xbuf,stats1);
  k_prep2<<<22,256,0,stream>>>(stats1,g1,be1,W1,al1,ar1,b1,rW1,wbuf);
  k_cast<<<CBLK,256,0,stream>>>(xbuf,Abf);
  k_matmul64<<<MBLK,256,0,stream>>>(xbuf,wbuf,wbuf+4096,hacc,0);
  for(int r=0;r<3;r++){
    float* fr=wbuf+4160+r*WRSTRIDE;
    int csroff=(r==0)?0:(r==1)?E_RES:(E_RES+E_SEQ);
    k_mfmaC<<<MBLK,256,0,stream>>>(Abf,fr,Ybf);
    k_el<<<NBLK,256,0,stream>>>(xbuf,fr,EL);
    k_aggf<<<ABLK,256,0,stream>>>(Ybf,EL,rowptr+r*RPS,csr+csroff,hacc);
  }
  k_matmul64<<<MBLK,256,0,stream>>>(hacc,fcW1,fcb1,(float*)d_out,1);
}

// Round 7
// 799.121 us; speedup vs baseline: 1.1219x; 1.1219x over previous
//
#include <hip/hip_runtime.h>
#include <math.h>

#define NN    50000
#define DD    64
#define HH    4
#define E_RES 400000
#define E_SEQ 100000
#define E_KNN 400000
#define SCH   4096
#define SNB   ((NN + SCH - 1)/SCH)   // 13 chunks per relation
#define RPS   (NN + 4)               // rowptr stride (16B-aligned per relation)
#define WRSTRIDE 8968                // floats per relation in wbuf

typedef __attribute__((ext_vector_type(8))) short short8;
typedef __attribute__((ext_vector_type(4))) float floatx4;

__device__ inline unsigned short f2bf(float f){
  union{float f; unsigned u;} v; v.f=f;
  unsigned r = v.u + 0x7FFF + ((v.u>>16)&1);
  return (unsigned short)(r>>16);
}
__device__ inline float bf2f(unsigned short u){
  union{unsigned u; float f;} v; v.u=(unsigned)u<<16; return v.f;
}

// ---------------- CSR build ----------------
__global__ void k_hist(const int* __restrict__ dst, int E, int* __restrict__ cnt){
  int i = blockIdx.x*256 + threadIdx.x;
  if(i<E) atomicAdd(&cnt[dst[i]], 1);
}

__global__ void __launch_bounds__(256)
k_blocksum(const int* __restrict__ hist, int* __restrict__ bsums){
  int r = blockIdx.x / SNB, b = blockIdx.x % SNB;
  const int* cnt = hist + r*NN;
  int t = threadIdx.x;
  int end = min((b+1)*SCH, NN);
  int s = 0;
  for(int j = b*SCH + t; j < end; j += 256) s += cnt[j];
  __shared__ int sh[4];
  for(int off=32; off; off>>=1) s += __shfl_down(s, off, 64);
  int lane = t & 63, w = t >> 6;
  if(lane==0) sh[w]=s;
  __syncthreads();
  if(t==0) bsums[blockIdx.x] = sh[0]+sh[1]+sh[2]+sh[3];
}

__global__ void __launch_bounds__(256)
k_scanwrite(const int* __restrict__ hist, const int* __restrict__ bsums,
            int* __restrict__ rowptr, int* __restrict__ cursor){
  int r = blockIdx.x / SNB, b = blockIdx.x % SNB;
  const int* cnt = hist + r*NN;
  int* rp  = rowptr + r*RPS;
  int* cur = cursor + r*NN;
  __shared__ int sh_off;
  __shared__ int wtot[4];
  int t = threadIdx.x;
  if(t==0){
    int o=0, tot=0;
    for(int i=0;i<SNB;i++){ int v=bsums[r*SNB+i]; if(i<b) o+=v; tot+=v; }
    sh_off=o;
    if(b==0) rp[NN]=tot;
  }
  int base = b*SCH + t*16;
  int v[16];
  bool full = (base+16 <= NN);
  if(full){
    int4 a0=((const int4*)cnt)[base/4+0];
    int4 a1=((const int4*)cnt)[base/4+1];
    int4 a2=((const int4*)cnt)[base/4+2];
    int4 a3=((const int4*)cnt)[base/4+3];
    v[0]=a0.x;v[1]=a0.y;v[2]=a0.z;v[3]=a0.w;
    v[4]=a1.x;v[5]=a1.y;v[6]=a1.z;v[7]=a1.w;
    v[8]=a2.x;v[9]=a2.y;v[10]=a2.z;v[11]=a2.w;
    v[12]=a3.x;v[13]=a3.y;v[14]=a3.z;v[15]=a3.w;
  } else {
    for(int j=0;j<16;j++){ int idx=base+j; v[j]=(idx<NN)?cnt[idx]:0; }
  }
  int loc=0;
  #pragma unroll
  for(int j=0;j<16;j++) loc += v[j];
  int lane = t & 63, w = t >> 6;
  int inc = loc;
  for(int off=1; off<64; off<<=1){ int n=__shfl_up(inc, off, 64); if(lane>=off) inc+=n; }
  if(lane==63) wtot[w]=inc;
  __syncthreads();
  int woff=0;
  for(int i=0;i<w;i++) woff += wtot[i];
  int run = sh_off + woff + inc - loc;
  if(full){
    int o[16];
    #pragma unroll
    for(int j=0;j<16;j++){ o[j]=run; run+=v[j]; }
    ((int4*)rp )[base/4+0]=make_int4(o[0],o[1],o[2],o[3]);
    ((int4*)rp )[base/4+1]=make_int4(o[4],o[5],o[6],o[7]);
    ((int4*)rp )[base/4+2]=make_int4(o[8],o[9],o[10],o[11]);
    ((int4*)rp )[base/4+3]=make_int4(o[12],o[13],o[14],o[15]);
    ((int4*)cur)[base/4+0]=make_int4(o[0],o[1],o[2],o[3]);
    ((int4*)cur)[base/4+1]=make_int4(o[4],o[5],o[6],o[7]);
    ((int4*)cur)[base/4+2]=make_int4(o[8],o[9],o[10],o[11]);
    ((int4*)cur)[base/4+3]=make_int4(o[12],o[13],o[14],o[15]);
  } else {
    for(int j=0;j<16;j++){
      int idx=base+j;
      if(idx<NN){ rp[idx]=run; cur[idx]=run; run+=v[j]; }
    }
  }
}

__global__ void k_scatter(const int* __restrict__ src, const int* __restrict__ dst,
                          int E, int* __restrict__ cursor, int* __restrict__ csr){
  int i = blockIdx.x*256 + threadIdx.x;
  if(i<E){ int pos = atomicAdd(&cursor[dst[i]],1); csr[pos]=src[i]; }
}

// ---------------- BN stats ----------------
__global__ void k_bnstats(const float* __restrict__ x, float* __restrict__ stats){
  __shared__ float sh[512];
  int t = threadIdx.x, col = t & 63, rg = t >> 6;
  float s=0.f, q=0.f;
  for(int row = blockIdx.x*4 + rg; row < NN; row += gridDim.x*4){
    float v = x[(size_t)row*64 + col]; s += v; q += v*v;
  }
  sh[t]=s; sh[256+t]=q; __syncthreads();
  if(rg==0){
    s = sh[col]+sh[64+col]+sh[128+col]+sh[192+col];
    q = sh[256+col]+sh[320+col]+sh[384+col]+sh[448+col];
    atomicAdd(&stats[col], s); atomicAdd(&stats[64+col], q);
  }
}

// ---------------- fold BN into weights (parallel) ---------------------------
__global__ void __launch_bounds__(256)
k_prep2(const float* __restrict__ stats, const float* __restrict__ g,
        const float* __restrict__ be, const float* __restrict__ W,
        const float* __restrict__ al, const float* __restrict__ ar,
        const float* __restrict__ b, const float* __restrict__ rW,
        float* __restrict__ wbuf){
  __shared__ float scale[64], shift[64];
  __shared__ float red[256];
  int t = threadIdx.x;
  if(t<64){
    float mu  = stats[t]*(1.0f/NN);
    float var = stats[64+t]*(1.0f/NN) - mu*mu;
    float sc  = g[t]*rsqrtf(var + 1e-5f);
    scale[t]=sc; shift[t]=be[t]-mu*sc;
  }
  __syncthreads();
  int bid = blockIdx.x;
  if(bid < 12){
    int r = bid >> 2, c0 = (bid & 3)*64;
    float* fr = wbuf + 4160 + r*WRSTRIDE;
    unsigned short* Wt = (unsigned short*)fr;
    float* bo = fr + 8192;
    int cl = c0 + (t & 63), kg = t >> 6;
    int h = cl >> 6, d = cl & 63, cp = d*4 + h;
    float bias = 0.f;
    #pragma unroll
    for(int j=0;j<16;j++){
      int k = kg*16 + j;
      float w = W[((size_t)(r*64+k))*256 + cl];
      bias += shift[k]*w;
      Wt[cp*64 + k] = f2bf(scale[k]*w);
    }
    red[t]=bias; __syncthreads();
    if(kg==0) bo[cp] = red[t] + red[t+64] + red[t+128] + red[t+192];
  } else if(bid < 18){
    int wv = (bid-12)*4 + (t>>6);        // 0..23
    int r = wv >> 3, cc = wv & 7, h = cc & 3, k = t & 63;
    const float* av = ((cc>=4)?ar:al) + (r*HH+h)*64;
    const float* Wk = W + ((size_t)(r*64+k))*256 + h*64;
    float w=0.f;
    for(int d2=0; d2<64; d2++) w += Wk[d2]*av[d2];
    float* fr = wbuf + 4160 + r*WRSTRIDE;
    (fr + 8448)[cc*64 + k] = scale[k]*w;   // Wel
    float bp = shift[k]*w;
    for(int off=32; off; off>>=1) bp += __shfl_down(bp, off, 64);
    if(k==0) (fr + 8960)[cc] = bp;         // biasE
  } else {
    int db = (bid-18)*16;
    int d = db + (t & 15), kg = t >> 4;
    float bias = 0.f;
    #pragma unroll
    for(int j=0;j<4;j++){
      int k = kg*4 + j;
      float w = 0.f;
      for(int r=0;r<3;r++)
        for(int h=0;h<HH;h++)
          w += rW[((size_t)(r*64+k))*256 + h*64 + d];
      w *= 0.25f;
      bias += shift[k]*w;
      wbuf[k*64+d] = scale[k]*w;
    }
    red[t]=bias; __syncthreads();
    if(t<16){
      float s=0.f;
      for(int i=t;i<256;i+=16) s += red[i];
      int dd = db + t;
      float bb=0.f;
      for(int r=0;r<3;r++) for(int h=0;h<HH;h++) bb += b[r*256 + h*64 + dd];
      wbuf[4096+dd] = s + 0.25f*bb;
    }
  }
}

// ---------------- cast activations f32 -> bf16 ------------------------------
__global__ void __launch_bounds__(256)
k_cast(const float* __restrict__ X, unsigned short* __restrict__ out){
  int i = blockIdx.x*256 + threadIdx.x;   // one float4 per thread
  float4 v = ((const float4*)X)[i];
  ushort4 o;
  o.x=f2bf(v.x); o.y=f2bf(v.y); o.z=f2bf(v.z); o.w=f2bf(v.w);
  ((ushort4*)out)[i]=o;
}

// ---------------- MFMA matmul: Ybf[N,256] = Abf[N,64] @ W + bias ------------
__global__ void __launch_bounds__(256)
k_mfmaC(const unsigned short* __restrict__ Abf, const float* __restrict__ fr,
        unsigned short* __restrict__ Ybf){
  const unsigned short* Wt = (const unsigned short*)fr;
  const float* biasC = fr + 8192;
  int t = threadIdx.x;
  int wv = t>>6, lane = t&63;
  int m = lane&15, kq = lane>>4;       // kq=0..3
  int row = blockIdx.x*64 + wv*16 + m;
  int rc = row < NN ? row : NN-1;
  short8 a0 = *(const short8*)(Abf + (size_t)rc*64 + kq*8);
  short8 a1 = *(const short8*)(Abf + (size_t)rc*64 + 32 + kq*8);
  int orow = blockIdx.x*64 + wv*16 + kq*4;
  for(int ct=0; ct<16; ct++){
    int col = ct*16 + m;
    const unsigned short* wp = Wt + (size_t)col*64 + kq*8;
    short8 b0 = *(const short8*)(wp);
    short8 b1 = *(const short8*)(wp + 32);
    floatx4 acc = {0.f,0.f,0.f,0.f};
    acc = __builtin_amdgcn_mfma_f32_16x16x32_bf16(a0, b0, acc, 0,0,0);
    acc = __builtin_amdgcn_mfma_f32_16x16x32_bf16(a1, b1, acc, 0,0,0);
    float bs = biasC[col];
    #pragma unroll
    for(int ri=0; ri<4; ri++){
      int ro = orow + ri;
      if(ro < NN) Ybf[(size_t)ro*256 + col] = f2bf(acc[ri] + bs);
    }
  }
}

// ---------------- el/er: EL[N,8] = A[N,64] @ Wel (f32, exact) ---------------
__global__ void __launch_bounds__(256)
k_el(const float* __restrict__ A, const float* __restrict__ fr,
     float* __restrict__ EL){
  const float* Wel = fr + 8448;
  const float* biasE = fr + 8960;
  __shared__ float sw[512];
  __shared__ float sb[8];
  int t = threadIdx.x;
  sw[t]=Wel[t]; sw[256+t]=Wel[256+t];
  if(t<8) sb[t]=biasE[t];
  __syncthreads();
  int n = blockIdx.x*256 + t;
  if(n>=NN) return;
  float acc[8];
  #pragma unroll
  for(int c=0;c<8;c++) acc[c]=sb[c];
  const float4* Ar = (const float4*)(A + (size_t)n*64);
  #pragma unroll
  for(int kq=0;kq<16;kq++){
    float4 a = Ar[kq];
    #pragma unroll
    for(int c=0;c<8;c++){
      const float* w = sw + c*64 + kq*4;
      acc[c] += a.x*w[0] + a.y*w[1] + a.z*w[2] + a.w*w[3];
    }
  }
  ((float4*)EL)[n*2]   = make_float4(acc[0],acc[1],acc[2],acc[3]);
  ((float4*)EL)[n*2+1] = make_float4(acc[4],acc[5],acc[6],acc[7]);
}

// ---------------- matmul: [NN,64] @ [64,64] + bias (opt relu) ----------------
__global__ void __launch_bounds__(256)
k_matmul64(const float* __restrict__ A, const float* __restrict__ W,
           const float* __restrict__ bias, float* __restrict__ Y, int relu){
  __shared__ float xs[4096];
  int t = threadIdx.x;
  int row0 = blockIdx.x*64;
  for(int f=t; f<1024; f+=256){
    int r=f>>4; int row=row0+r;
    float4 v = (row<NN) ? ((const float4*)A)[(size_t)row*16 + (f&15)]
                        : make_float4(0.f,0.f,0.f,0.f);
    ((float4*)xs)[f]=v;
  }
  __syncthreads();
  int c = t & 63, rg = t >> 6;
  float wreg[64];
  #pragma unroll
  for(int k=0;k<64;k++) wreg[k]=W[k*64+c];
  float bs = bias[c];
  for(int r=rg*16; r<rg*16+16; r++){
    int row=row0+r; if(row>=NN) continue;
    float acc=bs;
    #pragma unroll
    for(int k=0;k<64;k++) acc += xs[r*64+k]*wreg[k];
    if(relu) acc=fmaxf(acc,0.f);
    Y[(size_t)row*64+c]=acc;
  }
}

// ---------------- edge coefficients: one THREAD per dst node ----------------
__global__ void __launch_bounds__(256)
k_edgecoef(const float* __restrict__ EL, const int* __restrict__ rowptr,
           const int* __restrict__ csr, float4* __restrict__ coef){
  int n = blockIdx.x*256 + threadIdx.x;
  if(n>=NN) return;
  int beg = rowptr[n], end = rowptr[n+1];
  if(end<=beg) return;
  const float4 er = ((const float4*)EL)[n*2+1];
  float m0=-1e30f,m1=-1e30f,m2=-1e30f,m3=-1e30f;
  float s0=0.f,s1=0.f,s2=0.f,s3=0.f;
  for(int i=beg;i<end;i++){
    int src = csr[i];
    float4 el = ((const float4*)EL)[src*2];
    float e0=el.x+er.x, e1=el.y+er.y, e2=el.z+er.z, e3=el.w+er.w;
    e0 = e0>0.f? e0 : 0.2f*e0;
    e1 = e1>0.f? e1 : 0.2f*e1;
    e2 = e2>0.f? e2 : 0.2f*e2;
    e3 = e3>0.f? e3 : 0.2f*e3;
    float n0=fmaxf(m0,e0); s0=s0*__expf(m0-n0)+__expf(e0-n0); m0=n0;
    float n1=fmaxf(m1,e1); s1=s1*__expf(m1-n1)+__expf(e1-n1); m1=n1;
    float n2=fmaxf(m2,e2); s2=s2*__expf(m2-n2)+__expf(e2-n2); m2=n2;
    float n3=fmaxf(m3,e3); s3=s3*__expf(m3-n3)+__expf(e3-n3); m3=n3;
    coef[i] = make_float4(e0,e1,e2,e3);
  }
  float r0=1.f/s0, r1=1.f/s1, r2=1.f/s2, r3=1.f/s3;
  for(int i=beg;i<end;i++){
    float4 e = coef[i];
    coef[i] = make_float4(__expf(e.x-m0)*r0, __expf(e.y-m1)*r1,
                          __expf(e.z-m2)*r2, __expf(e.w-m3)*r3);
  }
}

// ---------------- weighted gather, 4-wide MLP: one WAVE per dst node --------
__global__ void __launch_bounds__(256)
k_agg2(const unsigned short* __restrict__ Ybf, const int* __restrict__ rowptr,
       const int* __restrict__ csr, const float4* __restrict__ coef,
       float* __restrict__ hacc){
  int wid  = (blockIdx.x*256 + threadIdx.x) >> 6;
  int lane = threadIdx.x & 63;
  if(wid>=NN) return;
  int beg = rowptr[wid], end = rowptr[wid+1];
  if(end<=beg) return;
  float a0=0.f, a1=0.f, a2=0.f, a3=0.f;
  int i = beg;
  for(; i+4<=end; i+=4){
    int  s0=csr[i],  s1=csr[i+1], s2=csr[i+2], s3=csr[i+3];
    float4 c0=coef[i],   c1=coef[i+1], c2=coef[i+2], c3=coef[i+3];
    ushort4 y0 = *(const ushort4*)(Ybf + ((size_t)s0<<8) + lane*4);
    ushort4 y1 = *(const ushort4*)(Ybf + ((size_t)s1<<8) + lane*4);
    ushort4 y2 = *(const ushort4*)(Ybf + ((size_t)s2<<8) + lane*4);
    ushort4 y3 = *(const ushort4*)(Ybf + ((size_t)s3<<8) + lane*4);
    a0 += c0.x*bf2f(y0.x)+c0.y*bf2f(y0.y)+c0.z*bf2f(y0.z)+c0.w*bf2f(y0.w);
    a1 += c1.x*bf2f(y1.x)+c1.y*bf2f(y1.y)+c1.z*bf2f(y1.z)+c1.w*bf2f(y1.w);
    a2 += c2.x*bf2f(y2.x)+c2.y*bf2f(y2.y)+c2.z*bf2f(y2.z)+c2.w*bf2f(y2.w);
    a3 += c3.x*bf2f(y3.x)+c3.y*bf2f(y3.y)+c3.z*bf2f(y3.z)+c3.w*bf2f(y3.w);
  }
  for(; i<end; i++){
    int s=csr[i];
    float4 c=coef[i];
    ushort4 y = *(const ushort4*)(Ybf + ((size_t)s<<8) + lane*4);
    a0 += c.x*bf2f(y.x)+c.y*bf2f(y.y)+c.z*bf2f(y.z)+c.w*bf2f(y.w);
  }
  hacc[(size_t)wid*64 + lane] += 0.25f*(a0+a1+a2+a3);
}

extern "C" void kernel_launch(void* const* d_in, const int* in_sizes, int n_in,
                              void* d_out, int out_size, void* d_ws, size_t ws_size,
                              hipStream_t stream){
  const float* x      =(const float*)d_in[0];
  const int* src_res  =(const int*)d_in[1];
  const int* dst_res  =(const int*)d_in[2];
  const int* src_seq  =(const int*)d_in[3];
  const int* dst_seq  =(const int*)d_in[4];
  const int* src_knn  =(const int*)d_in[5];
  const int* dst_knn  =(const int*)d_in[6];
  const float* W0 =(const float*)d_in[7];
  const float* al0=(const float*)d_in[8];
  const float* ar0=(const float*)d_in[9];
  const float* b0 =(const float*)d_in[10];
  const float* rW0=(const float*)d_in[11];
  const float* W1 =(const float*)d_in[12];
  const float* al1=(const float*)d_in[13];
  const float* ar1=(const float*)d_in[14];
  const float* b1 =(const float*)d_in[15];
  const float* rW1=(const float*)d_in[16];
  const float* fcW0=(const float*)d_in[17];
  const float* fcb0=(const float*)d_in[18];
  const float* fcW1=(const float*)d_in[19];
  const float* fcb1=(const float*)d_in[20];
  const float* g0 =(const float*)d_in[21];
  const float* be0=(const float*)d_in[22];
  const float* g1 =(const float*)d_in[23];
  const float* be1=(const float*)d_in[24];

  char* ws=(char*)d_ws;
  int*   hist   =(int*)  (ws+0);               // 3*NN ints
  float* stats0 =(float*)(ws+600000);
  float* stats1 =(float*)(ws+600512);
  int*   rowptr =(int*)  (ws+601024);          // 3*RPS ints
  int*   cursor =(int*)  (ws+1201088);
  int*   csr    =(int*)  (ws+1801088);         // 900000 ints
  float* wbuf   =(float*)(ws+5401088);         // 31064 f
  int*   bsums  =(int*)  (ws+5525344);         // 39 ints
  unsigned short* Abf =(unsigned short*)(ws+5526528);  // NN*64 bf16 = 6.4MB
  unsigned short* Ybf =(unsigned short*)(ws+11926528UL); // NN*256 bf16 = 25.6MB
  float* hacc   =(float*)(ws+37526528UL);      // NN*64 f
  float* xbuf   =(float*)(ws+50326528UL);      // NN*64 f
  float* EL     =(float*)(ws+63126528UL);      // NN*8 f
  float4* coef  =(float4*)(ws+64726528UL);     // 400000 float4

  hipMemsetAsync(ws, 0, 601024, stream);  // hist + both stats buffers

  k_hist<<<(E_RES+255)/256,256,0,stream>>>(dst_res,E_RES,hist);
  k_hist<<<(E_SEQ+255)/256,256,0,stream>>>(dst_seq,E_SEQ,hist+NN);
  k_hist<<<(E_KNN+255)/256,256,0,stream>>>(dst_knn,E_KNN,hist+2*NN);
  k_blocksum<<<3*SNB,256,0,stream>>>(hist,bsums);
  k_scanwrite<<<3*SNB,256,0,stream>>>(hist,bsums,rowptr,cursor);
  k_scatter<<<(E_RES+255)/256,256,0,stream>>>(src_res,dst_res,E_RES,cursor,csr);
  k_scatter<<<(E_SEQ+255)/256,256,0,stream>>>(src_seq,dst_seq,E_SEQ,cursor+NN,csr+E_RES);
  k_scatter<<<(E_KNN+255)/256,256,0,stream>>>(src_knn,dst_knn,E_KNN,cursor+2*NN,csr+E_RES+E_SEQ);

  const int MBLK=(NN+63)/64;   // 782
  const int NBLK=(NN+255)/256; // 196
  const int CBLK=(NN*64)/(256*4); // 3125 (exact)
  // ---- layer 1 ----
  k_bnstats<<<256,256,0,stream>>>(x,stats0);
  k_prep2<<<22,256,0,stream>>>(stats0,g0,be0,W0,al0,ar0,b0,rW0,wbuf);
  k_cast<<<CBLK,256,0,stream>>>(x,Abf);
  k_matmul64<<<MBLK,256,0,stream>>>(x,wbuf,wbuf+4096,hacc,0);   // residual+bias, head-meaned
  for(int r=0;r<3;r++){
    float* fr=wbuf+4160+r*WRSTRIDE;
    int csroff=(r==0)?0:(r==1)?E_RES:(E_RES+E_SEQ);
    k_mfmaC<<<MBLK,256,0,stream>>>(Abf,fr,Ybf);
    k_el<<<NBLK,256,0,stream>>>(x,fr,EL);
    k_edgecoef<<<NBLK,256,0,stream>>>(EL,rowptr+r*RPS,csr+csroff,coef);
    k_agg2<<<(NN*64)/256,256,0,stream>>>(Ybf,rowptr+r*RPS,csr+csroff,coef,hacc);
  }
  k_matmul64<<<MBLK,256,0,stream>>>(hacc,fcW0,fcb0,xbuf,1);
  // ---- layer 2 ----
  k_bnstats<<<256,256,0,stream>>>(xbuf,stats1);
  k_prep2<<<22,256,0,stream>>>(stats1,g1,be1,W1,al1,ar1,b1,rW1,wbuf);
  k_cast<<<CBLK,256,0,stream>>>(xbuf,Abf);
  k_matmul64<<<MBLK,256,0,stream>>>(xbuf,wbuf,wbuf+4096,hacc,0);
  for(int r=0;r<3;r++){
    float* fr=wbuf+4160+r*WRSTRIDE;
    int csroff=(r==0)?0:(r==1)?E_RES:(E_RES+E_SEQ);
    k_mfmaC<<<MBLK,256,0,stream>>>(Abf,fr,Ybf);
    k_el<<<NBLK,256,0,stream>>>(xbuf,fr,EL);
    k_edgecoef<<<NBLK,256,0,stream>>>(EL,rowptr+r*RPS,csr+csroff,coef);
    k_agg2<<<(NN*64)/256,256,0,stream>>>(Ybf,rowptr+r*RPS,csr+csroff,coef,hacc);
  }
  k_matmul64<<<MBLK,256,0,stream>>>(hacc,fcW1,fcb1,(float*)d_out,1);
}

// Round 8
// 658.961 us; speedup vs baseline: 1.3605x; 1.2127x over previous
//
#include <hip/hip_runtime.h>
#include <math.h>

#define NN    50000
#define DD    64
#define HH    4
#define E_RES 400000
#define E_SEQ 100000
#define E_KNN 400000
#define ETOT  (E_RES+E_SEQ+E_KNN)
#define SCH   4096
#define SNB   ((NN + SCH - 1)/SCH)   // 13 chunks per relation
#define RPS   (NN + 4)               // rowptr stride (16B-aligned per relation)
#define WRSTRIDE 8968                // floats per relation in wbuf
#define MBLK  ((NN+63)/64)           // 782
#define NBLK  ((NN+255)/256)         // 196

typedef __attribute__((ext_vector_type(8))) short short8;
typedef __attribute__((ext_vector_type(4))) float floatx4;

__device__ inline unsigned short f2bf(float f){
  union{float f; unsigned u;} v; v.f=f;
  unsigned r = v.u + 0x7FFF + ((v.u>>16)&1);
  return (unsigned short)(r>>16);
}
__device__ inline float bf2f(unsigned short u){
  union{unsigned u; float f;} v; v.u=(unsigned)u<<16; return v.f;
}

// ---------------- CSR build (merged over 3 relations) -----------------------
__global__ void k_hist3(const int* __restrict__ d0, const int* __restrict__ d1,
                        const int* __restrict__ d2, int* __restrict__ cnt){
  int i = blockIdx.x*256 + threadIdx.x;
  if(i < E_RES)                atomicAdd(&cnt[d0[i]], 1);
  else if(i < E_RES+E_SEQ)     atomicAdd(&cnt[NN + d1[i-E_RES]], 1);
  else if(i < ETOT)            atomicAdd(&cnt[2*NN + d2[i-E_RES-E_SEQ]], 1);
}

__global__ void __launch_bounds__(256)
k_blocksum(const int* __restrict__ hist, int* __restrict__ bsums){
  int r = blockIdx.x / SNB, b = blockIdx.x % SNB;
  const int* cnt = hist + r*NN;
  int t = threadIdx.x;
  int end = min((b+1)*SCH, NN);
  int s = 0;
  for(int j = b*SCH + t; j < end; j += 256) s += cnt[j];
  __shared__ int sh[4];
  for(int off=32; off; off>>=1) s += __shfl_down(s, off, 64);
  int lane = t & 63, w = t >> 6;
  if(lane==0) sh[w]=s;
  __syncthreads();
  if(t==0) bsums[blockIdx.x] = sh[0]+sh[1]+sh[2]+sh[3];
}

__global__ void __launch_bounds__(256)
k_scanwrite(const int* __restrict__ hist, const int* __restrict__ bsums,
            int* __restrict__ rowptr, int* __restrict__ cursor){
  int r = blockIdx.x / SNB, b = blockIdx.x % SNB;
  const int* cnt = hist + r*NN;
  int* rp  = rowptr + r*RPS;
  int* cur = cursor + r*NN;
  __shared__ int sh_off;
  __shared__ int wtot[4];
  int t = threadIdx.x;
  if(t==0){
    int o=0, tot=0;
    for(int i=0;i<SNB;i++){ int v=bsums[r*SNB+i]; if(i<b) o+=v; tot+=v; }
    sh_off=o;
    if(b==0) rp[NN]=tot;
  }
  int base = b*SCH + t*16;
  int v[16];
  bool full = (base+16 <= NN);
  if(full){
    int4 a0=((const int4*)cnt)[base/4+0];
    int4 a1=((const int4*)cnt)[base/4+1];
    int4 a2=((const int4*)cnt)[base/4+2];
    int4 a3=((const int4*)cnt)[base/4+3];
    v[0]=a0.x;v[1]=a0.y;v[2]=a0.z;v[3]=a0.w;
    v[4]=a1.x;v[5]=a1.y;v[6]=a1.z;v[7]=a1.w;
    v[8]=a2.x;v[9]=a2.y;v[10]=a2.z;v[11]=a2.w;
    v[12]=a3.x;v[13]=a3.y;v[14]=a3.z;v[15]=a3.w;
  } else {
    for(int j=0;j<16;j++){ int idx=base+j; v[j]=(idx<NN)?cnt[idx]:0; }
  }
  int loc=0;
  #pragma unroll
  for(int j=0;j<16;j++) loc += v[j];
  int lane = t & 63, w = t >> 6;
  int inc = loc;
  for(int off=1; off<64; off<<=1){ int n=__shfl_up(inc, off, 64); if(lane>=off) inc+=n; }
  if(lane==63) wtot[w]=inc;
  __syncthreads();
  int woff=0;
  for(int i=0;i<w;i++) woff += wtot[i];
  int run = sh_off + woff + inc - loc;
  if(full){
    int o[16];
    #pragma unroll
    for(int j=0;j<16;j++){ o[j]=run; run+=v[j]; }
    ((int4*)rp )[base/4+0]=make_int4(o[0],o[1],o[2],o[3]);
    ((int4*)rp )[base/4+1]=make_int4(o[4],o[5],o[6],o[7]);
    ((int4*)rp )[base/4+2]=make_int4(o[8],o[9],o[10],o[11]);
    ((int4*)rp )[base/4+3]=make_int4(o[12],o[13],o[14],o[15]);
    ((int4*)cur)[base/4+0]=make_int4(o[0],o[1],o[2],o[3]);
    ((int4*)cur)[base/4+1]=make_int4(o[4],o[5],o[6],o[7]);
    ((int4*)cur)[base/4+2]=make_int4(o[8],o[9],o[10],o[11]);
    ((int4*)cur)[base/4+3]=make_int4(o[12],o[13],o[14],o[15]);
  } else {
    for(int j=0;j<16;j++){
      int idx=base+j;
      if(idx<NN){ rp[idx]=run; cur[idx]=run; run+=v[j]; }
    }
  }
}

__global__ void k_scatter3(const int* __restrict__ s0, const int* __restrict__ d0,
                           const int* __restrict__ s1, const int* __restrict__ d1,
                           const int* __restrict__ s2, const int* __restrict__ d2,
                           int* __restrict__ cursor, int* __restrict__ csr){
  int i = blockIdx.x*256 + threadIdx.x;
  if(i < E_RES){
    int pos = atomicAdd(&cursor[d0[i]],1); csr[pos]=s0[i];
  } else if(i < E_RES+E_SEQ){
    int j=i-E_RES;
    int pos = atomicAdd(&cursor[NN+d1[j]],1); csr[E_RES+pos]=s1[j];
  } else if(i < ETOT){
    int j=i-E_RES-E_SEQ;
    int pos = atomicAdd(&cursor[2*NN+d2[j]],1); csr[E_RES+E_SEQ+pos]=s2[j];
  }
}

// ---------------- BN stats + bf16 cast (fused) ------------------------------
__global__ void k_bnstats(const float* __restrict__ x, float* __restrict__ stats,
                          unsigned short* __restrict__ Abf){
  __shared__ float sh[512];
  int t = threadIdx.x, col = t & 63, rg = t >> 6;
  float s=0.f, q=0.f;
  for(int row = blockIdx.x*4 + rg; row < NN; row += gridDim.x*4){
    float v = x[(size_t)row*64 + col]; s += v; q += v*v;
    Abf[(size_t)row*64 + col] = f2bf(v);
  }
  sh[t]=s; sh[256+t]=q; __syncthreads();
  if(rg==0){
    s = sh[col]+sh[64+col]+sh[128+col]+sh[192+col];
    q = sh[256+col]+sh[320+col]+sh[384+col]+sh[448+col];
    atomicAdd(&stats[col], s); atomicAdd(&stats[64+col], q);
  }
}

// ---------------- fold BN into weights (parallel) ---------------------------
__global__ void __launch_bounds__(256)
k_prep2(const float* __restrict__ stats, const float* __restrict__ g,
        const float* __restrict__ be, const float* __restrict__ W,
        const float* __restrict__ al, const float* __restrict__ ar,
        const float* __restrict__ b, const float* __restrict__ rW,
        float* __restrict__ wbuf){
  __shared__ float scale[64], shift[64];
  __shared__ float red[256];
  int t = threadIdx.x;
  if(t<64){
    float mu  = stats[t]*(1.0f/NN);
    float var = stats[64+t]*(1.0f/NN) - mu*mu;
    float sc  = g[t]*rsqrtf(var + 1e-5f);
    scale[t]=sc; shift[t]=be[t]-mu*sc;
  }
  __syncthreads();
  int bid = blockIdx.x;
  if(bid < 12){
    int r = bid >> 2, c0 = (bid & 3)*64;
    float* fr = wbuf + 4160 + r*WRSTRIDE;
    unsigned short* Wt = (unsigned short*)fr;
    float* bo = fr + 8192;
    int cl = c0 + (t & 63), kg = t >> 6;
    int h = cl >> 6, d = cl & 63, cp = d*4 + h;
    float bias = 0.f;
    #pragma unroll
    for(int j=0;j<16;j++){
      int k = kg*16 + j;
      float w = W[((size_t)(r*64+k))*256 + cl];
      bias += shift[k]*w;
      Wt[cp*64 + k] = f2bf(scale[k]*w);
    }
    red[t]=bias; __syncthreads();
    if(kg==0) bo[cp] = red[t] + red[t+64] + red[t+128] + red[t+192];
  } else if(bid < 18){
    int wv = (bid-12)*4 + (t>>6);        // 0..23
    int r = wv >> 3, cc = wv & 7, h = cc & 3, k = t & 63;
    const float* av = ((cc>=4)?ar:al) + (r*HH+h)*64;
    const float* Wk = W + ((size_t)(r*64+k))*256 + h*64;
    float w=0.f;
    for(int d2=0; d2<64; d2++) w += Wk[d2]*av[d2];
    float* fr = wbuf + 4160 + r*WRSTRIDE;
    (fr + 8448)[cc*64 + k] = scale[k]*w;   // Wel
    float bp = shift[k]*w;
    for(int off=32; off; off>>=1) bp += __shfl_down(bp, off, 64);
    if(k==0) (fr + 8960)[cc] = bp;         // biasE
  } else {
    int db = (bid-18)*16;
    int d = db + (t & 15), kg = t >> 4;
    float bias = 0.f;
    #pragma unroll
    for(int j=0;j<4;j++){
      int k = kg*4 + j;
      float w = 0.f;
      for(int r=0;r<3;r++)
        for(int h=0;h<HH;h++)
          w += rW[((size_t)(r*64+k))*256 + h*64 + d];
      w *= 0.25f;
      bias += shift[k]*w;
      wbuf[k*64+d] = scale[k]*w;
    }
    red[t]=bias; __syncthreads();
    if(t<16){
      float s=0.f;
      for(int i=t;i<256;i+=16) s += red[i];
      int dd = db + t;
      float bb=0.f;
      for(int r=0;r<3;r++) for(int h=0;h<HH;h++) bb += b[r*256 + h*64 + dd];
      wbuf[4096+dd] = s + 0.25f*bb;
    }
  }
}

// ---------------- MFMA matmul (all 3 relations): Ybf[r][N,256] --------------
__global__ void __launch_bounds__(256)
k_mfmaC3(const unsigned short* __restrict__ Abf, const float* __restrict__ wbuf,
         unsigned short* __restrict__ Ybf){
  int r = blockIdx.x / MBLK, blk = blockIdx.x % MBLK;
  const float* fr = wbuf + 4160 + r*WRSTRIDE;
  const unsigned short* Wt = (const unsigned short*)fr;
  const float* biasC = fr + 8192;
  unsigned short* Yr = Ybf + (size_t)r*NN*256;
  int t = threadIdx.x;
  int wv = t>>6, lane = t&63;
  int m = lane&15, kq = lane>>4;       // kq=0..3
  int row = blk*64 + wv*16 + m;
  int rc = row < NN ? row : NN-1;
  short8 a0 = *(const short8*)(Abf + (size_t)rc*64 + kq*8);
  short8 a1 = *(const short8*)(Abf + (size_t)rc*64 + 32 + kq*8);
  int orow = blk*64 + wv*16 + kq*4;
  for(int ct=0; ct<16; ct++){
    int col = ct*16 + m;
    const unsigned short* wp = Wt + (size_t)col*64 + kq*8;
    short8 b0 = *(const short8*)(wp);
    short8 b1 = *(const short8*)(wp + 32);
    floatx4 acc = {0.f,0.f,0.f,0.f};
    acc = __builtin_amdgcn_mfma_f32_16x16x32_bf16(a0, b0, acc, 0,0,0);
    acc = __builtin_amdgcn_mfma_f32_16x16x32_bf16(a1, b1, acc, 0,0,0);
    float bs = biasC[col];
    #pragma unroll
    for(int ri=0; ri<4; ri++){
      int ro = orow + ri;
      if(ro < NN) Yr[(size_t)ro*256 + col] = f2bf(acc[ri] + bs);
    }
  }
}

// ---------------- MFMA matmul 64x64: out[N,64] = Abf @ W + bias (opt relu) --
// W given as f32 [k][c] (64x64); staged to LDS bf16 transposed [c][k].
__global__ void __launch_bounds__(256)
k_mfma64(const unsigned short* __restrict__ Abf, const float* __restrict__ Wf,
         const float* __restrict__ bias, float* __restrict__ out, int relu){
  __shared__ unsigned short Wt[4096];
  __shared__ float bs[64];
  int t = threadIdx.x;
  for(int idx=t; idx<4096; idx+=256){
    int c = idx>>6, k = idx&63;
    Wt[idx] = f2bf(Wf[k*64+c]);
  }
  if(t<64) bs[t]=bias[t];
  __syncthreads();
  int wv = t>>6, lane = t&63, m = lane&15, kq = lane>>4;
  int row = blockIdx.x*64 + wv*16 + m;
  int rc = row < NN ? row : NN-1;
  short8 a0 = *(const short8*)(Abf + (size_t)rc*64 + kq*8);
  short8 a1 = *(const short8*)(Abf + (size_t)rc*64 + 32 + kq*8);
  int orow = blockIdx.x*64 + wv*16 + kq*4;
  #pragma unroll
  for(int ct=0; ct<4; ct++){
    int col = ct*16 + m;
    short8 b0 = *(const short8*)(Wt + col*64 + kq*8);
    short8 b1 = *(const short8*)(Wt + col*64 + 32 + kq*8);
    floatx4 acc = {0.f,0.f,0.f,0.f};
    acc = __builtin_amdgcn_mfma_f32_16x16x32_bf16(a0, b0, acc, 0,0,0);
    acc = __builtin_amdgcn_mfma_f32_16x16x32_bf16(a1, b1, acc, 0,0,0);
    float bb = bs[col];
    #pragma unroll
    for(int ri=0; ri<4; ri++){
      int ro = orow + ri;
      if(ro < NN){
        float v = acc[ri] + bb;
        if(relu) v = fmaxf(v, 0.f);
        out[(size_t)ro*64 + col] = v;
      }
    }
  }
}

// ---------------- el/er (all 3 relations): EL[r][N,8] -----------------------
__global__ void __launch_bounds__(256)
k_el3(const float* __restrict__ A, const float* __restrict__ wbuf,
      float* __restrict__ EL){
  int r = blockIdx.x / NBLK;
  const float* fr = wbuf + 4160 + r*WRSTRIDE;
  const float* Wel = fr + 8448;
  const float* biasE = fr + 8960;
  float* ELr = EL + (size_t)r*NN*8;
  __shared__ float sw[512];
  __shared__ float sb[8];
  int t = threadIdx.x;
  sw[t]=Wel[t]; sw[256+t]=Wel[256+t];
  if(t<8) sb[t]=biasE[t];
  __syncthreads();
  int n = (blockIdx.x % NBLK)*256 + t;
  if(n>=NN) return;
  float acc[8];
  #pragma unroll
  for(int c=0;c<8;c++) acc[c]=sb[c];
  const float4* Ar = (const float4*)(A + (size_t)n*64);
  #pragma unroll
  for(int kq=0;kq<16;kq++){
    float4 a = Ar[kq];
    #pragma unroll
    for(int c=0;c<8;c++){
      const float* w = sw + c*64 + kq*4;
      acc[c] += a.x*w[0] + a.y*w[1] + a.z*w[2] + a.w*w[3];
    }
  }
  ((float4*)ELr)[n*2]   = make_float4(acc[0],acc[1],acc[2],acc[3]);
  ((float4*)ELr)[n*2+1] = make_float4(acc[4],acc[5],acc[6],acc[7]);
}

// ---------------- edge coefficients (all 3 relations) -----------------------
__global__ void __launch_bounds__(256)
k_edgecoef3(const float* __restrict__ EL, const int* __restrict__ rowptr,
            const int* __restrict__ csr, float4* __restrict__ coef){
  int r = blockIdx.x / NBLK;
  const float* ELr = EL + (size_t)r*NN*8;
  const int* rp = rowptr + r*RPS;
  int off = (r==0)?0:(r==1)?E_RES:(E_RES+E_SEQ);
  const int* cs = csr + off;
  float4* cf = coef + off;
  int n = (blockIdx.x % NBLK)*256 + threadIdx.x;
  if(n>=NN) return;
  int beg = rp[n], end = rp[n+1];
  if(end<=beg) return;
  const float4 er = ((const float4*)ELr)[n*2+1];
  float m0=-1e30f,m1=-1e30f,m2=-1e30f,m3=-1e30f;
  float s0=0.f,s1=0.f,s2=0.f,s3=0.f;
  for(int i=beg;i<end;i++){
    int src = cs[i];
    float4 el = ((const float4*)ELr)[src*2];
    float e0=el.x+er.x, e1=el.y+er.y, e2=el.z+er.z, e3=el.w+er.w;
    e0 = e0>0.f? e0 : 0.2f*e0;
    e1 = e1>0.f? e1 : 0.2f*e1;
    e2 = e2>0.f? e2 : 0.2f*e2;
    e3 = e3>0.f? e3 : 0.2f*e3;
    float n0=fmaxf(m0,e0); s0=s0*__expf(m0-n0)+__expf(e0-n0); m0=n0;
    float n1=fmaxf(m1,e1); s1=s1*__expf(m1-n1)+__expf(e1-n1); m1=n1;
    float n2=fmaxf(m2,e2); s2=s2*__expf(m2-n2)+__expf(e2-n2); m2=n2;
    float n3=fmaxf(m3,e3); s3=s3*__expf(m3-n3)+__expf(e3-n3); m3=n3;
    cf[i] = make_float4(e0,e1,e2,e3);
  }
  float r0=1.f/s0, r1=1.f/s1, r2=1.f/s2, r3=1.f/s3;
  for(int i=beg;i<end;i++){
    float4 e = cf[i];
    cf[i] = make_float4(__expf(e.x-m0)*r0, __expf(e.y-m1)*r1,
                        __expf(e.z-m2)*r2, __expf(e.w-m3)*r3);
  }
}

// ---------------- weighted gather over ALL relations: one WAVE per node -----
// hacc(f32, residual) read once; final written as bf16 for the FC matmul.
__global__ void __launch_bounds__(256)
k_agg3(const unsigned short* __restrict__ Ybf, const int* __restrict__ rowptr,
       const int* __restrict__ csr, const float4* __restrict__ coef,
       const float* __restrict__ hacc, unsigned short* __restrict__ haccbf){
  int wid  = (blockIdx.x*256 + threadIdx.x) >> 6;
  int lane = threadIdx.x & 63;
  if(wid>=NN) return;
  float a = 0.f;
  #pragma unroll
  for(int r=0;r<3;r++){
    const int* rp = rowptr + r*RPS;
    int off = (r==0)?0:(r==1)?E_RES:(E_RES+E_SEQ);
    const int* cs = csr + off;
    const float4* cf = coef + off;
    const unsigned short* Yr = Ybf + (size_t)r*NN*256;
    int beg = rp[wid], end = rp[wid+1];
    float a0=0.f, a1=0.f, a2=0.f, a3=0.f;
    int i = beg;
    for(; i+4<=end; i+=4){
      int  s0=cs[i],  s1=cs[i+1], s2=cs[i+2], s3=cs[i+3];
      float4 c0=cf[i],   c1=cf[i+1], c2=cf[i+2], c3=cf[i+3];
      ushort4 y0 = *(const ushort4*)(Yr + ((size_t)s0<<8) + lane*4);
      ushort4 y1 = *(const ushort4*)(Yr + ((size_t)s1<<8) + lane*4);
      ushort4 y2 = *(const ushort4*)(Yr + ((size_t)s2<<8) + lane*4);
      ushort4 y3 = *(const ushort4*)(Yr + ((size_t)s3<<8) + lane*4);
      a0 += c0.x*bf2f(y0.x)+c0.y*bf2f(y0.y)+c0.z*bf2f(y0.z)+c0.w*bf2f(y0.w);
      a1 += c1.x*bf2f(y1.x)+c1.y*bf2f(y1.y)+c1.z*bf2f(y1.z)+c1.w*bf2f(y1.w);
      a2 += c2.x*bf2f(y2.x)+c2.y*bf2f(y2.y)+c2.z*bf2f(y2.z)+c2.w*bf2f(y2.w);
      a3 += c3.x*bf2f(y3.x)+c3.y*bf2f(y3.y)+c3.z*bf2f(y3.z)+c3.w*bf2f(y3.w);
    }
    for(; i<end; i++){
      int s=cs[i];
      float4 c=cf[i];
      ushort4 y = *(const ushort4*)(Yr + ((size_t)s<<8) + lane*4);
      a0 += c.x*bf2f(y.x)+c.y*bf2f(y.y)+c.z*bf2f(y.z)+c.w*bf2f(y.w);
    }
    a += a0+a1+a2+a3;
  }
  float fin = hacc[(size_t)wid*64 + lane] + 0.25f*a;
  haccbf[(size_t)wid*64 + lane] = f2bf(fin);
}

extern "C" void kernel_launch(void* const* d_in, const int* in_sizes, int n_in,
                              void* d_out, int out_size, void* d_ws, size_t ws_size,
                              hipStream_t stream){
  const float* x      =(const float*)d_in[0];
  const int* src_res  =(const int*)d_in[1];
  const int* dst_res  =(const int*)d_in[2];
  const int* src_seq  =(const int*)d_in[3];
  const int* dst_seq  =(const int*)d_in[4];
  const int* src_knn  =(const int*)d_in[5];
  const int* dst_knn  =(const int*)d_in[6];
  const float* W0 =(const float*)d_in[7];
  const float* al0=(const float*)d_in[8];
  const float* ar0=(const float*)d_in[9];
  const float* b0 =(const float*)d_in[10];
  const float* rW0=(const float*)d_in[11];
  const float* W1 =(const float*)d_in[12];
  const float* al1=(const float*)d_in[13];
  const float* ar1=(const float*)d_in[14];
  const float* b1 =(const float*)d_in[15];
  const float* rW1=(const float*)d_in[16];
  const float* fcW0=(const float*)d_in[17];
  const float* fcb0=(const float*)d_in[18];
  const float* fcW1=(const float*)d_in[19];
  const float* fcb1=(const float*)d_in[20];
  const float* g0 =(const float*)d_in[21];
  const float* be0=(const float*)d_in[22];
  const float* g1 =(const float*)d_in[23];
  const float* be1=(const float*)d_in[24];

  char* ws=(char*)d_ws;
  int*   hist   =(int*)  (ws+0);               // 3*NN ints
  float* stats0 =(float*)(ws+600000);
  float* stats1 =(float*)(ws+600512);
  int*   rowptr =(int*)  (ws+601024);          // 3*RPS ints
  int*   cursor =(int*)  (ws+1201088);
  int*   csr    =(int*)  (ws+1801088);         // 900000 ints
  float* wbuf   =(float*)(ws+5401088);         // 31064 f
  int*   bsums  =(int*)  (ws+5525344);         // 39 ints
  unsigned short* Abf  =(unsigned short*)(ws+5526528);   // NN*64 bf16 = 6.4MB
  unsigned short* Ybf  =(unsigned short*)(ws+11926528UL);// 3*NN*256 bf16 = 76.8MB
  float* hacc   =(float*)(ws+88726528UL);      // NN*64 f32
  unsigned short* haccbf=(unsigned short*)(ws+101526528UL); // NN*64 bf16
  float* xbuf   =(float*)(ws+107926528UL);     // NN*64 f32
  float* EL     =(float*)(ws+120726528UL);     // 3*NN*8 f32
  float4* coef  =(float4*)(ws+125526528UL);    // 900000 float4 = 14.4MB

  hipMemsetAsync(ws, 0, 601024, stream);  // hist + both stats buffers

  const int EBLK=(ETOT+255)/256;   // 3516
  k_hist3<<<EBLK,256,0,stream>>>(dst_res,dst_seq,dst_knn,hist);
  k_blocksum<<<3*SNB,256,0,stream>>>(hist,bsums);
  k_scanwrite<<<3*SNB,256,0,stream>>>(hist,bsums,rowptr,cursor);
  k_scatter3<<<EBLK,256,0,stream>>>(src_res,dst_res,src_seq,dst_seq,
                                    src_knn,dst_knn,cursor,csr);

  const int ABLK=(NN*64)/256;  // 12500 (exact)
  // ---- layer 1 ----
  k_bnstats<<<256,256,0,stream>>>(x,stats0,Abf);
  k_prep2<<<22,256,0,stream>>>(stats0,g0,be0,W0,al0,ar0,b0,rW0,wbuf);
  k_mfma64<<<MBLK,256,0,stream>>>(Abf,wbuf,wbuf+4096,hacc,0);   // residual (head-meaned)
  k_mfmaC3<<<3*MBLK,256,0,stream>>>(Abf,wbuf,Ybf);
  k_el3<<<3*NBLK,256,0,stream>>>(x,wbuf,EL);
  k_edgecoef3<<<3*NBLK,256,0,stream>>>(EL,rowptr,csr,coef);
  k_agg3<<<ABLK,256,0,stream>>>(Ybf,rowptr,csr,coef,hacc,haccbf);
  k_mfma64<<<MBLK,256,0,stream>>>(haccbf,fcW0,fcb0,xbuf,1);
  // ---- layer 2 ----
  k_bnstats<<<256,256,0,stream>>>(xbuf,stats1,Abf);
  k_prep2<<<22,256,0,stream>>>(stats1,g1,be1,W1,al1,ar1,b1,rW1,wbuf);
  k_mfma64<<<MBLK,256,0,stream>>>(Abf,wbuf,wbuf+4096,hacc,0);
  k_mfmaC3<<<3*MBLK,256,0,stream>>>(Abf,wbuf,Ybf);
  k_el3<<<3*NBLK,256,0,stream>>>(xbuf,wbuf,EL);
  k_edgecoef3<<<3*NBLK,256,0,stream>>>(EL,rowptr,csr,coef);
  k_agg3<<<ABLK,256,0,stream>>>(Ybf,rowptr,csr,coef,hacc,haccbf);
  k_mfma64<<<MBLK,256,0,stream>>>(haccbf,fcW1,fcb1,(float*)d_out,1);
}

// Round 9
// 570.530 us; speedup vs baseline: 1.5714x; 1.1550x over previous
//
#include <hip/hip_runtime.h>
#include <math.h>

#define NN    50000
#define DD    64
#define HH    4
#define E_RES 400000
#define E_SEQ 100000
#define E_KNN 400000
#define ETOT  (E_RES+E_SEQ+E_KNN)
#define SCH   4096
#define SNB   ((NN + SCH - 1)/SCH)   // 13 chunks per relation
#define RPS   (NN + 4)               // rowptr stride (16B-aligned per relation)
#define MBLK  ((NN+63)/64)           // 782
#define NBLK  ((NN+255)/256)         // 196
#define ZS    800                    // Z stride (shorts): 768 z + 3 flags + 29 pad
#define KTOT  864                    // fused matmul K: 64 (x) + 768 (z) + 3 + 29

// wbuf byte layout:
//   [0, 110592)        Wfused bf16 [col][j], col stride KTOT
//   [110592, 110848)   biasfused f32[64]
//   [110848 + r*2080)  per relation: Wel f32[512] + biasE f32[8]

typedef __attribute__((ext_vector_type(8))) short short8;
typedef __attribute__((ext_vector_type(4))) float floatx4;

__device__ inline unsigned short f2bf(float f){
  union{float f; unsigned u;} v; v.f=f;
  unsigned r = v.u + 0x7FFF + ((v.u>>16)&1);
  return (unsigned short)(r>>16);
}
__device__ inline float bf2f(unsigned short u){
  union{unsigned u; float f;} v; v.u=(unsigned)u<<16; return v.f;
}

// ---------------- CSR build (merged over 3 relations) -----------------------
__global__ void k_hist3(const int* __restrict__ d0, const int* __restrict__ d1,
                        const int* __restrict__ d2, int* __restrict__ cnt){
  int i = blockIdx.x*256 + threadIdx.x;
  if(i < E_RES)                atomicAdd(&cnt[d0[i]], 1);
  else if(i < E_RES+E_SEQ)     atomicAdd(&cnt[NN + d1[i-E_RES]], 1);
  else if(i < ETOT)            atomicAdd(&cnt[2*NN + d2[i-E_RES-E_SEQ]], 1);
}

__global__ void __launch_bounds__(256)
k_blocksum(const int* __restrict__ hist, int* __restrict__ bsums){
  int r = blockIdx.x / SNB, b = blockIdx.x % SNB;
  const int* cnt = hist + r*NN;
  int t = threadIdx.x;
  int end = min((b+1)*SCH, NN);
  int s = 0;
  for(int j = b*SCH + t; j < end; j += 256) s += cnt[j];
  __shared__ int sh[4];
  for(int off=32; off; off>>=1) s += __shfl_down(s, off, 64);
  int lane = t & 63, w = t >> 6;
  if(lane==0) sh[w]=s;
  __syncthreads();
  if(t==0) bsums[blockIdx.x] = sh[0]+sh[1]+sh[2]+sh[3];
}

__global__ void __launch_bounds__(256)
k_scanwrite(const int* __restrict__ hist, const int* __restrict__ bsums,
            int* __restrict__ rowptr, int* __restrict__ cursor){
  int r = blockIdx.x / SNB, b = blockIdx.x % SNB;
  const int* cnt = hist + r*NN;
  int* rp  = rowptr + r*RPS;
  int* cur = cursor + r*NN;
  __shared__ int sh_off;
  __shared__ int wtot[4];
  int t = threadIdx.x;
  if(t==0){
    int o=0, tot=0;
    for(int i=0;i<SNB;i++){ int v=bsums[r*SNB+i]; if(i<b) o+=v; tot+=v; }
    sh_off=o;
    if(b==0) rp[NN]=tot;
  }
  int base = b*SCH + t*16;
  int v[16];
  bool full = (base+16 <= NN);
  if(full){
    int4 a0=((const int4*)cnt)[base/4+0];
    int4 a1=((const int4*)cnt)[base/4+1];
    int4 a2=((const int4*)cnt)[base/4+2];
    int4 a3=((const int4*)cnt)[base/4+3];
    v[0]=a0.x;v[1]=a0.y;v[2]=a0.z;v[3]=a0.w;
    v[4]=a1.x;v[5]=a1.y;v[6]=a1.z;v[7]=a1.w;
    v[8]=a2.x;v[9]=a2.y;v[10]=a2.z;v[11]=a2.w;
    v[12]=a3.x;v[13]=a3.y;v[14]=a3.z;v[15]=a3.w;
  } else {
    for(int j=0;j<16;j++){ int idx=base+j; v[j]=(idx<NN)?cnt[idx]:0; }
  }
  int loc=0;
  #pragma unroll
  for(int j=0;j<16;j++) loc += v[j];
  int lane = t & 63, w = t >> 6;
  int inc = loc;
  for(int off=1; off<64; off<<=1){ int n=__shfl_up(inc, off, 64); if(lane>=off) inc+=n; }
  if(lane==63) wtot[w]=inc;
  __syncthreads();
  int woff=0;
  for(int i=0;i<w;i++) woff += wtot[i];
  int run = sh_off + woff + inc - loc;
  if(full){
    int o[16];
    #pragma unroll
    for(int j=0;j<16;j++){ o[j]=run; run+=v[j]; }
    ((int4*)rp )[base/4+0]=make_int4(o[0],o[1],o[2],o[3]);
    ((int4*)rp )[base/4+1]=make_int4(o[4],o[5],o[6],o[7]);
    ((int4*)rp )[base/4+2]=make_int4(o[8],o[9],o[10],o[11]);
    ((int4*)rp )[base/4+3]=make_int4(o[12],o[13],o[14],o[15]);
    ((int4*)cur)[base/4+0]=make_int4(o[0],o[1],o[2],o[3]);
    ((int4*)cur)[base/4+1]=make_int4(o[4],o[5],o[6],o[7]);
    ((int4*)cur)[base/4+2]=make_int4(o[8],o[9],o[10],o[11]);
    ((int4*)cur)[base/4+3]=make_int4(o[12],o[13],o[14],o[15]);
  } else {
    for(int j=0;j<16;j++){
      int idx=base+j;
      if(idx<NN){ rp[idx]=run; cur[idx]=run; run+=v[j]; }
    }
  }
}

__global__ void k_scatter3(const int* __restrict__ s0, const int* __restrict__ d0,
                           const int* __restrict__ s1, const int* __restrict__ d1,
                           const int* __restrict__ s2, const int* __restrict__ d2,
                           int* __restrict__ cursor, int* __restrict__ csr){
  int i = blockIdx.x*256 + threadIdx.x;
  if(i < E_RES){
    int pos = atomicAdd(&cursor[d0[i]],1); csr[pos]=s0[i];
  } else if(i < E_RES+E_SEQ){
    int j=i-E_RES;
    int pos = atomicAdd(&cursor[NN+d1[j]],1); csr[E_RES+pos]=s1[j];
  } else if(i < ETOT){
    int j=i-E_RES-E_SEQ;
    int pos = atomicAdd(&cursor[2*NN+d2[j]],1); csr[E_RES+E_SEQ+pos]=s2[j];
  }
}

// ---------------- BN stats + bf16 cast (fused) ------------------------------
__global__ void k_bnstats(const float* __restrict__ x, float* __restrict__ stats,
                          unsigned short* __restrict__ Abf){
  __shared__ float sh[512];
  int t = threadIdx.x, col = t & 63, rg = t >> 6;
  float s=0.f, q=0.f;
  for(int row = blockIdx.x*4 + rg; row < NN; row += gridDim.x*4){
    float v = x[(size_t)row*64 + col]; s += v; q += v*v;
    Abf[(size_t)row*64 + col] = f2bf(v);
  }
  sh[t]=s; sh[256+t]=q; __syncthreads();
  if(rg==0){
    s = sh[col]+sh[64+col]+sh[128+col]+sh[192+col];
    q = sh[256+col]+sh[320+col]+sh[384+col]+sh[448+col];
    atomicAdd(&stats[col], s); atomicAdd(&stats[64+col], q);
  }
}

// ---------------- prep: build fused weights ---------------------------------
// Wbig[KTOT][64] rows: 0..63 = scale_j*0.25*sum_{r,h} rW_r[j][h64+d]
//                      64+ (r*4+h)*64+c = 0.25*scale_c*W_r[c][h64+d]
//                      832+r = S_r[d] = 0.25*sum_h shift@W_r[:,h64+d]   (deg flags)
//                      835..863 = 0
// Wfused = Wbig @ fcW  (bf16),  biasfused = BH@fcW + fcb
// grid = 59: 0..51 main rows (16 j each), 52..57 Wel, 58 S/BH block.
__global__ void __launch_bounds__(256)
k_prep3(const float* __restrict__ stats, const float* __restrict__ g,
        const float* __restrict__ be, const float* __restrict__ W,
        const float* __restrict__ al, const float* __restrict__ ar,
        const float* __restrict__ b, const float* __restrict__ rW,
        const float* __restrict__ fcW, const float* __restrict__ fcb,
        float* __restrict__ wbufF){
  __shared__ float scale[64], shift[64];
  int t = threadIdx.x;
  if(t<64){
    float mu  = stats[t]*(1.0f/NN);
    float var = stats[64+t]*(1.0f/NN) - mu*mu;
    float sc  = g[t]*rsqrtf(var + 1e-5f);
    scale[t]=sc; shift[t]=be[t]-mu*sc;
  }
  __syncthreads();
  char* wb = (char*)wbufF;
  unsigned short* Wf = (unsigned short*)wbufF;
  float* biasF = (float*)(wb + 110592);
  int bid = blockIdx.x;
  if(bid < 52){
    __shared__ float fcWs[4096];
    for(int i=t;i<4096;i+=256) fcWs[i]=fcW[i];
    __syncthreads();
    int j = bid*16 + (t>>4);
    int cg = (t&15)*4;
    float Wrow[64];
    if(j < 64){
      for(int d=0; d<64; d++){
        float w=0.f;
        for(int r=0;r<3;r++)
          #pragma unroll
          for(int h=0;h<4;h++)
            w += rW[((size_t)(r*64+j))*256 + h*64 + d];
        Wrow[d] = scale[j]*0.25f*w;
      }
    } else {
      int jj = j-64;
      int r = jj>>8, hc = jj&255, h = hc>>6, c = hc&63;
      const float* Wp = W + ((size_t)(r*64+c))*256 + h*64;
      float sc = 0.25f*scale[c];
      #pragma unroll
      for(int d=0; d<64; d++) Wrow[d] = sc*Wp[d];
    }
    #pragma unroll
    for(int cc=0; cc<4; cc++){
      int col = cg+cc;
      float acc=0.f;
      #pragma unroll
      for(int d=0; d<64; d++) acc += Wrow[d]*fcWs[d*64+col];
      Wf[(size_t)col*KTOT + j] = f2bf(acc);
    }
  } else if(bid < 58){
    int wv = (bid-52)*4 + (t>>6);        // 0..23
    int r = wv >> 3, cc = wv & 7, h = cc & 3, k = t & 63;
    const float* av = ((cc>=4)?ar:al) + (r*HH+h)*64;
    const float* Wk = W + ((size_t)(r*64+k))*256 + h*64;
    float w=0.f;
    for(int d2=0; d2<64; d2++) w += Wk[d2]*av[d2];
    float* WelR = (float*)(wb + 110848 + r*2080);
    WelR[cc*64 + k] = scale[k]*w;
    float bp = shift[k]*w;
    for(int off=32; off; off>>=1) bp += __shfl_down(bp, off, 64);
    if(k==0) (WelR + 512)[cc] = bp;
  } else {
    __shared__ float S[3][64];
    __shared__ float BH[64];
    if(t<192){
      int r=t>>6, d=t&63;
      float s=0.f;
      #pragma unroll
      for(int h=0;h<4;h++){
        const float* Wp = W + (size_t)(r*64)*256 + h*64 + d;
        for(int k=0;k<64;k++) s += shift[k]*Wp[(size_t)k*256];
      }
      S[r][d]=0.25f*s;
    } else {
      int d = t-192;
      float s=0.f;
      for(int k=0;k<64;k++){
        float w=0.f;
        for(int r=0;r<3;r++)
          #pragma unroll
          for(int h=0;h<4;h++)
            w += rW[((size_t)(r*64+k))*256 + h*64 + d];
        s += shift[k]*0.25f*w;
      }
      float bb=0.f;
      for(int r=0;r<3;r++)
        #pragma unroll
        for(int h=0;h<4;h++) bb += b[r*256 + h*64 + d];
      BH[d] = s + 0.25f*bb;
    }
    __syncthreads();
    if(t<192){
      int r=t>>6, col=t&63;
      float acc=0.f;
      for(int d=0;d<64;d++) acc += S[r][d]*fcW[d*64+col];
      Wf[(size_t)col*KTOT + 832 + r] = f2bf(acc);
    } else {
      int col=t-192;
      float acc=0.f;
      for(int d=0;d<64;d++) acc += BH[d]*fcW[d*64+col];
      biasF[col] = acc + fcb[col];
    }
    if(t<64){
      for(int j=835;j<KTOT;j++) Wf[(size_t)t*KTOT + j] = 0;
    }
  }
}

// ---------------- el/er (all 3 relations): EL[r][N,8] -----------------------
__global__ void __launch_bounds__(256)
k_el3(const float* __restrict__ A, const float* __restrict__ wbufF,
      float* __restrict__ EL){
  int r = blockIdx.x / NBLK;
  const char* wb = (const char*)wbufF;
  const float* Wel = (const float*)(wb + 110848 + r*2080);
  const float* biasE = Wel + 512;
  float* ELr = EL + (size_t)r*NN*8;
  __shared__ float sw[512];
  __shared__ float sb[8];
  int t = threadIdx.x;
  sw[t]=Wel[t]; sw[256+t]=Wel[256+t];
  if(t<8) sb[t]=biasE[t];
  __syncthreads();
  int n = (blockIdx.x % NBLK)*256 + t;
  if(n>=NN) return;
  float acc[8];
  #pragma unroll
  for(int c=0;c<8;c++) acc[c]=sb[c];
  const float4* Ar = (const float4*)(A + (size_t)n*64);
  #pragma unroll
  for(int kq=0;kq<16;kq++){
    float4 a = Ar[kq];
    #pragma unroll
    for(int c=0;c<8;c++){
      const float* w = sw + c*64 + kq*4;
      acc[c] += a.x*w[0] + a.y*w[1] + a.z*w[2] + a.w*w[3];
    }
  }
  ((float4*)ELr)[n*2]   = make_float4(acc[0],acc[1],acc[2],acc[3]);
  ((float4*)ELr)[n*2+1] = make_float4(acc[4],acc[5],acc[6],acc[7]);
}

// ---------------- edge coefficients (all 3 relations) -----------------------
__global__ void __launch_bounds__(256)
k_edgecoef3(const float* __restrict__ EL, const int* __restrict__ rowptr,
            const int* __restrict__ csr, float4* __restrict__ coef){
  int r = blockIdx.x / NBLK;
  const float* ELr = EL + (size_t)r*NN*8;
  const int* rp = rowptr + r*RPS;
  int off = (r==0)?0:(r==1)?E_RES:(E_RES+E_SEQ);
  const int* cs = csr + off;
  float4* cf = coef + off;
  int n = (blockIdx.x % NBLK)*256 + threadIdx.x;
  if(n>=NN) return;
  int beg = rp[n], end = rp[n+1];
  if(end<=beg) return;
  const float4 er = ((const float4*)ELr)[n*2+1];
  float m0=-1e30f,m1=-1e30f,m2=-1e30f,m3=-1e30f;
  float s0=0.f,s1=0.f,s2=0.f,s3=0.f;
  for(int i=beg;i<end;i++){
    int src = cs[i];
    float4 el = ((const float4*)ELr)[src*2];
    float e0=el.x+er.x, e1=el.y+er.y, e2=el.z+er.z, e3=el.w+er.w;
    e0 = e0>0.f? e0 : 0.2f*e0;
    e1 = e1>0.f? e1 : 0.2f*e1;
    e2 = e2>0.f? e2 : 0.2f*e2;
    e3 = e3>0.f? e3 : 0.2f*e3;
    float n0=fmaxf(m0,e0); s0=s0*__expf(m0-n0)+__expf(e0-n0); m0=n0;
    float n1=fmaxf(m1,e1); s1=s1*__expf(m1-n1)+__expf(e1-n1); m1=n1;
    float n2=fmaxf(m2,e2); s2=s2*__expf(m2-n2)+__expf(e2-n2); m2=n2;
    float n3=fmaxf(m3,e3); s3=s3*__expf(m3-n3)+__expf(e3-n3); m3=n3;
    cf[i] = make_float4(e0,e1,e2,e3);
  }
  float r0=1.f/s0, r1=1.f/s1, r2=1.f/s2, r3=1.f/s3;
  for(int i=beg;i<end;i++){
    float4 e = cf[i];
    cf[i] = make_float4(__expf(e.x-m0)*r0, __expf(e.y-m1)*r1,
                        __expf(e.z-m2)*r2, __expf(e.w-m3)*r3);
  }
}

// ---------------- z-gather: one WAVE per node, gathers 128B x-rows ----------
// z[r*4+h][lane] = sum_e alpha_eh * x[src_e][lane]; +deg flags; pad zeroed.
__global__ void __launch_bounds__(256)
k_aggz(const unsigned short* __restrict__ Abf, const int* __restrict__ rowptr,
       const int* __restrict__ csr, const float4* __restrict__ coef,
       unsigned short* __restrict__ Zbf){
  int wid  = (blockIdx.x*256 + threadIdx.x) >> 6;
  int lane = threadIdx.x & 63;
  if(wid>=NN) return;
  float z[12];
  #pragma unroll
  for(int i=0;i<12;i++) z[i]=0.f;
  int fl0=0, fl1=0, fl2=0;
  #pragma unroll
  for(int r=0;r<3;r++){
    const int* rp = rowptr + r*RPS;
    int off = (r==0)?0:(r==1)?E_RES:(E_RES+E_SEQ);
    const int* cs = csr + off;
    const float4* cf = coef + off;
    int beg = rp[wid], end = rp[wid+1];
    if(r==0) fl0=(end>beg); else if(r==1) fl1=(end>beg); else fl2=(end>beg);
    float z0=0.f,z1=0.f,z2=0.f,z3=0.f;
    int i = beg;
    for(; i+4<=end; i+=4){
      int s0=cs[i], s1=cs[i+1], s2=cs[i+2], s3=cs[i+3];
      float4 c0=cf[i], c1=cf[i+1], c2=cf[i+2], c3=cf[i+3];
      float x0=bf2f(Abf[(size_t)s0*64+lane]);
      float x1=bf2f(Abf[(size_t)s1*64+lane]);
      float x2=bf2f(Abf[(size_t)s2*64+lane]);
      float x3=bf2f(Abf[(size_t)s3*64+lane]);
      z0 += c0.x*x0 + c1.x*x1 + c2.x*x2 + c3.x*x3;
      z1 += c0.y*x0 + c1.y*x1 + c2.y*x2 + c3.y*x3;
      z2 += c0.z*x0 + c1.z*x1 + c2.z*x2 + c3.z*x3;
      z3 += c0.w*x0 + c1.w*x1 + c2.w*x2 + c3.w*x3;
    }
    for(; i<end; i++){
      int s=cs[i];
      float4 c=cf[i];
      float x=bf2f(Abf[(size_t)s*64+lane]);
      z0 += c.x*x; z1 += c.y*x; z2 += c.z*x; z3 += c.w*x;
    }
    z[r*4+0]=z0; z[r*4+1]=z1; z[r*4+2]=z2; z[r*4+3]=z3;
  }
  size_t base = (size_t)wid*ZS;
  #pragma unroll
  for(int bk=0;bk<12;bk++) Zbf[base + bk*64 + lane] = f2bf(z[bk]);
  if(lane<32){
    unsigned short v = 0;
    if(lane==0) v = fl0 ? (unsigned short)0x3F80 : (unsigned short)0;
    if(lane==1) v = fl1 ? (unsigned short)0x3F80 : (unsigned short)0;
    if(lane==2) v = fl2 ? (unsigned short)0x3F80 : (unsigned short)0;
    Zbf[base + 768 + lane] = v;
  }
}

// ---------------- fused MFMA: out = relu([x|Z] @ Wfused + biasfused) --------
__global__ void __launch_bounds__(256)
k_mfmaZ(const unsigned short* __restrict__ Abf, const unsigned short* __restrict__ Zbf,
        const float* __restrict__ wbufF, float* __restrict__ out){
  const unsigned short* Wf = (const unsigned short*)wbufF;
  const float* biasF = (const float*)((const char*)wbufF + 110592);
  int t = threadIdx.x, wv = t>>6, lane = t&63, m = lane&15, kq = lane>>4;
  int row = blockIdx.x*64 + wv*16 + m;
  int rc = row < NN ? row : NN-1;
  floatx4 acc0 = {0.f,0.f,0.f,0.f};
  floatx4 acc1 = {0.f,0.f,0.f,0.f};
  floatx4 acc2 = {0.f,0.f,0.f,0.f};
  floatx4 acc3 = {0.f,0.f,0.f,0.f};
  const unsigned short* Arow = Abf + (size_t)rc*64;
  const unsigned short* Zrow = Zbf + (size_t)rc*ZS;
  for(int kb=0; kb<27; kb++){
    short8 a;
    if(kb<2) a = *(const short8*)(Arow + kb*32 + kq*8);
    else     a = *(const short8*)(Zrow + (kb-2)*32 + kq*8);
    int ko = kb*32 + kq*8;
    short8 b0 = *(const short8*)(Wf + (size_t)(0*16+m)*KTOT + ko);
    short8 b1 = *(const short8*)(Wf + (size_t)(1*16+m)*KTOT + ko);
    short8 b2 = *(const short8*)(Wf + (size_t)(2*16+m)*KTOT + ko);
    short8 b3 = *(const short8*)(Wf + (size_t)(3*16+m)*KTOT + ko);
    acc0 = __builtin_amdgcn_mfma_f32_16x16x32_bf16(a, b0, acc0, 0,0,0);
    acc1 = __builtin_amdgcn_mfma_f32_16x16x32_bf16(a, b1, acc1, 0,0,0);
    acc2 = __builtin_amdgcn_mfma_f32_16x16x32_bf16(a, b2, acc2, 0,0,0);
    acc3 = __builtin_amdgcn_mfma_f32_16x16x32_bf16(a, b3, acc3, 0,0,0);
  }
  int orow = blockIdx.x*64 + wv*16 + kq*4;
  #pragma unroll
  for(int ct=0; ct<4; ct++){
    int col = ct*16 + m;
    floatx4 acc = (ct==0)?acc0:(ct==1)?acc1:(ct==2)?acc2:acc3;
    float bb = biasF[col];
    #pragma unroll
    for(int ri=0; ri<4; ri++){
      int ro = orow + ri;
      if(ro < NN) out[(size_t)ro*64 + col] = fmaxf(acc[ri] + bb, 0.f);
    }
  }
}

extern "C" void kernel_launch(void* const* d_in, const int* in_sizes, int n_in,
                              void* d_out, int out_size, void* d_ws, size_t ws_size,
                              hipStream_t stream){
  const float* x      =(const float*)d_in[0];
  const int* src_res  =(const int*)d_in[1];
  const int* dst_res  =(const int*)d_in[2];
  const int* src_seq  =(const int*)d_in[3];
  const int* dst_seq  =(const int*)d_in[4];
  const int* src_knn  =(const int*)d_in[5];
  const int* dst_knn  =(const int*)d_in[6];
  const float* W0 =(const float*)d_in[7];
  const float* al0=(const float*)d_in[8];
  const float* ar0=(const float*)d_in[9];
  const float* b0 =(const float*)d_in[10];
  const float* rW0=(const float*)d_in[11];
  const float* W1 =(const float*)d_in[12];
  const float* al1=(const float*)d_in[13];
  const float* ar1=(const float*)d_in[14];
  const float* b1 =(const float*)d_in[15];
  const float* rW1=(const float*)d_in[16];
  const float* fcW0=(const float*)d_in[17];
  const float* fcb0=(const float*)d_in[18];
  const float* fcW1=(const float*)d_in[19];
  const float* fcb1=(const float*)d_in[20];
  const float* g0 =(const float*)d_in[21];
  const float* be0=(const float*)d_in[22];
  const float* g1 =(const float*)d_in[23];
  const float* be1=(const float*)d_in[24];

  char* ws=(char*)d_ws;
  int*   hist   =(int*)  (ws+0);               // 3*NN ints
  float* stats0 =(float*)(ws+600000);
  float* stats1 =(float*)(ws+600512);
  int*   rowptr =(int*)  (ws+601024);          // 3*RPS ints
  int*   cursor =(int*)  (ws+1201088);
  int*   csr    =(int*)  (ws+1801088);         // 900000 ints
  float* wbuf   =(float*)(ws+5401088);         // ~117 KB
  int*   bsums  =(int*)  (ws+5525344);         // 39 ints
  unsigned short* Abf =(unsigned short*)(ws+5526528);   // NN*64 bf16 = 6.4MB
  unsigned short* Zbf =(unsigned short*)(ws+11926528UL);// NN*ZS bf16 = 80MB
  float* xbuf   =(float*)(ws+91926528UL);      // NN*64 f32
  float* EL     =(float*)(ws+104726528UL);     // 3*NN*8 f32
  float4* coef  =(float4*)(ws+109526528UL);    // 900000 float4 = 14.4MB

  hipMemsetAsync(ws, 0, 601024, stream);  // hist + both stats buffers

  const int EBLK=(ETOT+255)/256;   // 3516
  k_hist3<<<EBLK,256,0,stream>>>(dst_res,dst_seq,dst_knn,hist);
  k_blocksum<<<3*SNB,256,0,stream>>>(hist,bsums);
  k_scanwrite<<<3*SNB,256,0,stream>>>(hist,bsums,rowptr,cursor);
  k_scatter3<<<EBLK,256,0,stream>>>(src_res,dst_res,src_seq,dst_seq,
                                    src_knn,dst_knn,cursor,csr);

  const int ABLK=(NN*64)/256;  // 12500 (exact)
  // ---- layer 1 ----
  k_bnstats<<<256,256,0,stream>>>(x,stats0,Abf);
  k_prep3<<<59,256,0,stream>>>(stats0,g0,be0,W0,al0,ar0,b0,rW0,fcW0,fcb0,wbuf);
  k_el3<<<3*NBLK,256,0,stream>>>(x,wbuf,EL);
  k_edgecoef3<<<3*NBLK,256,0,stream>>>(EL,rowptr,csr,coef);
  k_aggz<<<ABLK,256,0,stream>>>(Abf,rowptr,csr,coef,Zbf);
  k_mfmaZ<<<MBLK,256,0,stream>>>(Abf,Zbf,wbuf,xbuf);
  // ---- layer 2 ----
  k_bnstats<<<256,256,0,stream>>>(xbuf,stats1,Abf);
  k_prep3<<<59,256,0,stream>>>(stats1,g1,be1,W1,al1,ar1,b1,rW1,fcW1,fcb1,wbuf);
  k_el3<<<3*NBLK,256,0,stream>>>(xbuf,wbuf,EL);
  k_edgecoef3<<<3*NBLK,256,0,stream>>>(EL,rowptr,csr,coef);
  k_aggz<<<ABLK,256,0,stream>>>(Abf,rowptr,csr,coef,Zbf);
  k_mfmaZ<<<MBLK,256,0,stream>>>(Abf,Zbf,wbuf,(float*)d_out);
}